// Round 20
// baseline (311.484 us; speedup 1.0000x reference)
//
#include <hip/hip_runtime.h>
#include <hip/hip_fp16.h>
#include <math.h>

#define N_NODES 20000
#define T_STEPS 8
#define E_EDGES 640000
#define TN (T_STEPS * N_NODES)   // 160000
#define TE (T_STEPS * E_EDGES)   // 5120000
#define HDIM 32
#define HEADS 2
#define NPB 8                    // nodes per block for lane-parallel node kernels
#define SCAN_BLOCKS 625          // TN / 256 exactly
#define GB 32                    // histogram blocks per timestep
#define CHUNK (E_EDGES / GB)     // 20000 edges per histogram block
#define NPAIR (N_NODES / 2)      // packed bins per timestep
#define GNT 2                    // GRU nodes per thread-group (occupancy lever)
#define GNB (8 * GNT)            // GRU nodes per block = 16 (1250 blocks exactly)

__device__ __forceinline__ float lrelu02(float v) { return fmaxf(v, 0.2f * v); }
__device__ __forceinline__ float eluf(float v) { return v > 0.f ? v : expm1f(v); }
__device__ __forceinline__ float fsig(float v) {
    return __fdividef(1.f, 1.f + __expf(-v));
}
__device__ __forceinline__ float ftanh(float v) {
    return 1.f - __fdividef(2.f, __expf(2.f * v) + 1.f);
}

__device__ __forceinline__ float lane32_sum(float v) {
    v += __shfl_xor(v, 16);
    v += __shfl_xor(v, 8);
    v += __shfl_xor(v, 4);
    v += __shfl_xor(v, 2);
    v += __shfl_xor(v, 1);
    return v;
}

// load 4 fp16 channels (8 B, one dword2) -> float4
__device__ __forceinline__ float4 ldh4(const __half* p) {
    uint2 u = *(const uint2*)p;
    __half2 a = *(__half2*)&u.x;
    __half2 b = *(__half2*)&u.y;
    float2 f0 = __half22float2(a);
    float2 f1 = __half22float2(b);
    return make_float4(f0.x, f0.y, f1.x, f1.y);
}

// ---- pass A: per-block LDS histogram + local scan + locally-sorted staging.
// Outputs: hist8 (u8 counts), lrow16 (u16 local CSR offsets), stagedG (src
// values dst-sorted WITHIN the block's private 40 KB window -> L2-hot, one
// writeback; kills round-19's cross-block es line churn).
__global__ void k_hist(const int* __restrict__ ei, unsigned char* __restrict__ hist8,
                       unsigned short* __restrict__ lrow16,
                       unsigned short* __restrict__ stagedG) {
    __shared__ int lh[NPAIR];      // 40 KB: counts -> packed lrow
    __shared__ int partial[512];
    int t = blockIdx.y, b = blockIdx.x;
    for (int i = threadIdx.x; i < NPAIR; i += 512) lh[i] = 0;
    __syncthreads();
    const int* srcp = ei + (size_t)t * 2 * E_EDGES + b * CHUNK;
    const int* dstp = srcp + E_EDGES;
    for (int j = threadIdx.x; j < CHUNK; j += 512) {
        int dst = dstp[j];
        atomicAdd(&lh[dst >> 1], (dst & 1) ? 65536 : 1);
    }
    __syncthreads();
    size_t bi = (size_t)t * GB + b;
    // write u8 counts (max per-block bin ~12)
    unsigned char* hp = hist8 + bi * N_NODES;
    for (int i = threadIdx.x; i < NPAIR; i += 512) {
        int v = lh[i];
        uchar2 pk;
        pk.x = (unsigned char)(v & 0xff);
        pk.y = (unsigned char)((v >> 16) & 0xff);
        *(uchar2*)(hp + 2 * i) = pk;
    }
    __syncthreads();
    // exclusive scan over interleaved (low,high) counts; 20 pairs/thread
    const int tpp = 20;
    int i0 = threadIdx.x * tpp;
    int run = 0;
    for (int k = 0; k < tpp; ++k) {
        int i = i0 + k;
        if (i < NPAIR) {
            int v = lh[i];
            run += (v & 0xffff) + (v >> 16);
        }
    }
    partial[threadIdx.x] = run;
    __syncthreads();
    for (int off = 1; off < 512; off <<= 1) {
        int add = (threadIdx.x >= off) ? partial[threadIdx.x - off] : 0;
        __syncthreads();
        partial[threadIdx.x] += add;
        __syncthreads();
    }
    int run2 = (threadIdx.x > 0) ? partial[threadIdx.x - 1] : 0;
    for (int k = 0; k < tpp; ++k) {
        int i = i0 + k;
        if (i < NPAIR) {
            int v = lh[i];
            int c0 = v & 0xffff, c1 = v >> 16;
            lh[i] = run2 | ((run2 + c0) << 16);   // packed (l0, l1)
            run2 += c0 + c1;
        }
    }
    __syncthreads();
    // write l0 only (l1 = l0 + c0 derivable in scatter)
    unsigned short* lp = lrow16 + bi * NPAIR;
    for (int i = threadIdx.x; i < NPAIR; i += 512)
        lp[i] = (unsigned short)(lh[i] & 0xffff);
    // fill staged window via atomic position assignment (private 40 KB,
    // L2-hot random u16 stores; written back once)
    unsigned short* stg = stagedG + bi * CHUNK;
    for (int j = threadIdx.x; j < CHUNK; j += 512) {
        int src = srcp[j];
        int dst = dstp[j];
        int old = atomicAdd(&lh[dst >> 1], (dst & 1) ? 65536 : 1);
        int pos = (old >> (16 * (dst & 1))) & 0xffff;
        stg[pos] = (unsigned short)src;
    }
}

// ---- pass B: per-(t,dst) prefix over blocks -> base (packed) + totals.
// Thread (0,0) also does the tiny GAT1 rank-1 prep (folds k_prep launch).
__global__ void k_blkpre(const unsigned char* __restrict__ hist8, int* __restrict__ base,
                         int* __restrict__ cnt, const float* __restrict__ W1,
                         const float* __restrict__ as1, const float* __restrict__ ad1,
                         float* __restrict__ S4) {
    int i = blockIdx.x * blockDim.x + threadIdx.x;  // (t, pair)
    if (i == 0) {
        for (int hd = 0; hd < HEADS; ++hd) {
            float ss = 0.f, sd = 0.f;
            for (int c = 0; c < HDIM; ++c) {
                ss += W1[hd * HDIM + c] * as1[hd * HDIM + c];
                sd += W1[hd * HDIM + c] * ad1[hd * HDIM + c];
            }
            S4[hd] = ss;
            S4[HEADS + hd] = sd;
        }
    }
    if (i >= T_STEPS * NPAIR) return;
    int t = i / NPAIR, pr = i % NPAIR;
    int a0 = 0, a1 = 0;
    for (int b = 0; b < GB; ++b) {
        size_t bi = ((size_t)t * GB + b);
        uchar2 v = *(const uchar2*)(hist8 + bi * N_NODES + 2 * pr);
        base[bi * NPAIR + pr] = a0 | (a1 << 16);
        a0 += v.x;
        a1 += v.y;
    }
    cnt[t * N_NODES + 2 * pr] = a0;
    cnt[t * N_NODES + 2 * pr + 1] = a1;
}

// ---- scan (exclusive) over cnt[TN] -> row[TN+1] ----
__global__ void k_scan_a(const int* __restrict__ cnt, int* __restrict__ bsum) {
    __shared__ int s[256];
    int i = blockIdx.x * 256 + threadIdx.x;
    s[threadIdx.x] = (i < TN) ? cnt[i] : 0;
    __syncthreads();
    for (int off = 128; off > 0; off >>= 1) {
        if (threadIdx.x < off) s[threadIdx.x] += s[threadIdx.x + off];
        __syncthreads();
    }
    if (threadIdx.x == 0) bsum[blockIdx.x] = s[0];
}

__global__ void k_scan_b(const int* __restrict__ bsum, int* __restrict__ bpre) {
    __shared__ int s[256];
    __shared__ int carry;
    if (threadIdx.x == 0) carry = 0;
    __syncthreads();
    for (int base = 0; base < SCAN_BLOCKS; base += 256) {
        int i = base + threadIdx.x;
        int v = (i < SCAN_BLOCKS) ? bsum[i] : 0;
        s[threadIdx.x] = v;
        __syncthreads();
        for (int off = 1; off < 256; off <<= 1) {
            int add = (threadIdx.x >= off) ? s[threadIdx.x - off] : 0;
            __syncthreads();
            s[threadIdx.x] += add;
            __syncthreads();
        }
        if (i < SCAN_BLOCKS) bpre[i] = carry + s[threadIdx.x] - v;  // exclusive
        __syncthreads();
        if (threadIdx.x == 0) carry += s[255];
        __syncthreads();
    }
}

__global__ void k_scan_c(const int* __restrict__ cnt, const int* __restrict__ bpre,
                         int* __restrict__ row) {
    __shared__ int s[256];
    int i = blockIdx.x * 256 + threadIdx.x;
    int v = (i < TN) ? cnt[i] : 0;
    s[threadIdx.x] = v;
    __syncthreads();
    for (int off = 1; off < 256; off <<= 1) {
        int add = (threadIdx.x >= off) ? s[threadIdx.x - off] : 0;
        __syncthreads();
        s[threadIdx.x] += add;
        __syncthreads();
    }
    if (i < TN) row[i] = bpre[blockIdx.x] + s[threadIdx.x] - v;
    if (blockIdx.x == 0 && threadIdx.x == 0) row[TN] = TE;
}

// ---- pass C: per-bin copy from locally-sorted staging into global CSR.
// All blocks of a timestep sweep dst in increasing order -> es stores are a
// monotone sweep, lines filled by temporally-adjacent stores (no churn).
// XCD-pinned per timestep (t = blockIdx.x & 7).
__global__ void k_scatter(const unsigned char* __restrict__ hist8,
                          const unsigned short* __restrict__ lrow16,
                          const int* __restrict__ row, const int* __restrict__ base,
                          const unsigned short* __restrict__ stagedG,
                          unsigned short* __restrict__ es) {
    int t = blockIdx.x & 7;
    int b = blockIdx.x >> 3;          // 0..31
    size_t bi = (size_t)t * GB + b;
    const unsigned char* h8 = hist8 + bi * N_NODES;
    const unsigned short* lr = lrow16 + bi * NPAIR;
    const int* bs = base + bi * NPAIR;
    const unsigned short* stg = stagedG + bi * CHUNK;
    const int* rw = row + t * N_NODES;
    for (int i = threadIdx.x; i < NPAIR; i += blockDim.x) {
        uchar2 c = *(const uchar2*)(h8 + 2 * i);
        int l0 = lr[i];
        int l1 = l0 + c.x;
        int bp = bs[i];
        int b0 = bp & 0xffff, b1 = (bp >> 16) & 0xffff;
        int2 rr = *(const int2*)(rw + 2 * i);
        for (int k = 0; k < c.x; ++k) es[rr.x + b0 + k] = stg[l0 + k];
        for (int k = 0; k < c.y; ++k) es[rr.y + b1 + k] = stg[l1 + k];
    }
}

// ---- GAT1 reduce: ONE THREAD per (t,dst) bin; ushort4 es loads + unroll-4 ----
__global__ void k_gat1red(const unsigned short* __restrict__ es, const int* __restrict__ row,
                          const float* __restrict__ x, const float* __restrict__ S4,
                          float* __restrict__ inv) {
    int wid = blockIdx.x * 256 + threadIdx.x;  // grid exact: 625*256 == TN
    int t = wid / N_NODES;
    int start = row[wid], end = row[wid + 1];
    float Ss0 = S4[0], Ss1 = S4[1], Sd0 = S4[2], Sd1 = S4[3];
    float xd = x[wid];
    float a0 = xd * Sd0, a1 = xd * Sd1;
    const float* xt = x + (size_t)t * N_NODES;
    // self-loop init
    float w0 = __expf(lrelu02(fmaf(xd, Ss0, a0))), w1 = __expf(lrelu02(fmaf(xd, Ss1, a1)));
    float d0 = w0, n0 = w0 * xd, d1 = w1, n1 = w1 * xd;

#define G1E(xs) { \
    float v0 = __expf(lrelu02(fmaf(xs, Ss0, a0))); \
    float v1 = __expf(lrelu02(fmaf(xs, Ss1, a1))); \
    d0 += v0; n0 = fmaf(v0, xs, n0); \
    d1 += v1; n1 = fmaf(v1, xs, n1); }

    int p = start;
    // head: align to 4
    {
        int nh = (4 - (start & 3)) & 3;
        if (nh > end - start) nh = end - start;
        if (nh > 0) {
            float xa = xt[es[p]];
            float xb = (nh > 1) ? xt[es[p + 1]] : 0.f;
            float xc = (nh > 2) ? xt[es[p + 2]] : 0.f;
            G1E(xa)
            if (nh > 1) G1E(xb)
            if (nh > 2) G1E(xc)
            p += nh;
        }
    }
    for (; p + 3 < end; p += 4) {
        ushort4 e4 = *(const ushort4*)(es + p);
        float xa = xt[e4.x], xb = xt[e4.y], xc = xt[e4.z], xe = xt[e4.w];
        float va0 = __expf(lrelu02(fmaf(xa, Ss0, a0)));
        float va1 = __expf(lrelu02(fmaf(xa, Ss1, a1)));
        float vb0 = __expf(lrelu02(fmaf(xb, Ss0, a0)));
        float vb1 = __expf(lrelu02(fmaf(xb, Ss1, a1)));
        float vc0 = __expf(lrelu02(fmaf(xc, Ss0, a0)));
        float vc1 = __expf(lrelu02(fmaf(xc, Ss1, a1)));
        float ve0 = __expf(lrelu02(fmaf(xe, Ss0, a0)));
        float ve1 = __expf(lrelu02(fmaf(xe, Ss1, a1)));
        d0 += va0 + vb0 + vc0 + ve0;
        d1 += va1 + vb1 + vc1 + ve1;
        n0 = fmaf(va0, xa, fmaf(vb0, xb, fmaf(vc0, xc, fmaf(ve0, xe, n0))));
        n1 = fmaf(va1, xa, fmaf(vb1, xb, fmaf(vc1, xc, fmaf(ve1, xe, n1))));
    }
    {
        int nt = end - p;
        if (nt > 0) {
            float xa = xt[es[p]];
            float xb = (nt > 1) ? xt[es[p + 1]] : 0.f;
            float xc = (nt > 2) ? xt[es[p + 2]] : 0.f;
            G1E(xa)
            if (nt > 1) G1E(xb)
            if (nt > 2) G1E(xc)
        }
    }
#undef G1E
    inv[(size_t)wid * 2 + 0] = n0 / (d0 + 1e-16f);
    inv[(size_t)wid * 2 + 1] = n1 / (d1 + 1e-16f);
}

// ---- GAT1 epilogue + h2 = elu(z1) @ W2 (stored FP16: 64B row = 1 cache line)
// + src-logit as2 stored FP16 (40KB/t table: L1-resident in gat2red).
__global__ void k_node1(const float* __restrict__ inv, const float* __restrict__ W1,
                        const float* __restrict__ b1, const float* __restrict__ W2,
                        const float* __restrict__ as2w, const float* __restrict__ ad2w,
                        __half* __restrict__ h2h, __half* __restrict__ sh,
                        float* __restrict__ ad2) {
    __shared__ float sW1[HEADS * HDIM];
    __shared__ float sb1[HEADS * HDIM];
    __shared__ float sW2[HEADS * HDIM * (HDIM + 1)];
    __shared__ float sas[HDIM], sad[HDIM];
    __shared__ float z1s[NPB][HEADS * HDIM + 1];

    for (int i = threadIdx.x; i < HEADS * HDIM; i += blockDim.x) {
        sW1[i] = W1[i];
        sb1[i] = b1[i];
    }
    for (int i = threadIdx.x; i < HEADS * HDIM * HDIM; i += blockDim.x) {
        int k = i >> 5, c = i & 31;
        sW2[k * (HDIM + 1) + c] = W2[i];
    }
    for (int i = threadIdx.x; i < HDIM; i += blockDim.x) {
        sas[i] = as2w[i];
        sad[i] = ad2w[i];
    }
    __syncthreads();

    int ln = threadIdx.x >> 5;
    int c = threadIdx.x & 31;
    int tn = blockIdx.x * NPB + ln;
    if (tn >= TN) return;

    float inv0 = inv[(size_t)tn * 2 + 0];
    float inv1 = inv[(size_t)tn * 2 + 1];
    z1s[ln][c] = eluf(inv0 * sW1[c] + sb1[c]);
    z1s[ln][HDIM + c] = eluf(inv1 * sW1[HDIM + c] + sb1[HDIM + c]);
    __syncthreads();

    float acc = 0.f;
#pragma unroll
    for (int k = 0; k < HEADS * HDIM; ++k)
        acc += z1s[ln][k] * sW2[k * (HDIM + 1) + c];

    h2h[(size_t)tn * HDIM + c] = __float2half_rn(acc);
    float s = lane32_sum(acc * sas[c]);
    float d = lane32_sum(acc * sad[c]);
    if (c == 0) {
        sh[tn] = __float2half_rn(s);   // src logit (fp16)
        ad2[tn] = d;
    }
}

// ---- GAT2 reduce: ONE WAVE per block (8 nodes x 8 channel-quads).
// Per edge: 1 fp16 logit (L1-resident 40KB table) + 1 h2 line. Direct
// w = __expf(lrelu(sv+ad)) — trans pipe idle, no eab L2 gather.
__global__ void k_gat2red(const unsigned short* __restrict__ es, const int* __restrict__ row,
                          const __half* __restrict__ sh, const float* __restrict__ ad2,
                          const __half* __restrict__ h2h, const float* __restrict__ b2,
                          float* __restrict__ z2) {
    int b = blockIdx.x;
    int t = b & 7;            // XCD pin: blocks on one XCD share one timestep
    int chunk = b >> 3;       // 0..2499
    int lane = threadIdx.x;   // block = 64 threads = 1 wave
    int u = lane >> 3;        // node slot 0..7
    int l = lane & 7;         // channel quad: channels 4l..4l+3
    int node = chunk * 8 + u; // exact: 2500*8 == 20000
    int wid = t * N_NODES + node;

    int start = row[wid], end = row[wid + 1];
    float ad = ad2[wid];
    const __half* sht = sh + (size_t)t * N_NODES;
    const __half* h2t = h2h + (size_t)t * N_NODES * HDIM;

    float4 acc = make_float4(0.f, 0.f, 0.f, 0.f);
    float den = 0.f;

#define G2W(sv) __expf(lrelu02(__half2float(sht[sv]) + ad))
#define G2E(sv) { \
    float w = G2W(sv); \
    float4 hv = ldh4(h2t + (size_t)(sv) * HDIM + 4 * l); \
    acc.x = fmaf(w, hv.x, acc.x); \
    acc.y = fmaf(w, hv.y, acc.y); \
    acc.z = fmaf(w, hv.z, acc.z); \
    acc.w = fmaf(w, hv.w, acc.w); \
    den += w; }

    int p = start;
    // head: align p to 4 (<=3 edges; independent scalar loads)
    {
        int nh = (4 - (start & 3)) & 3;
        if (nh > end - start) nh = end - start;
        if (nh > 0) {
            int sh0 = es[p];
            int sh1 = (nh > 1) ? es[p + 1] : 0;
            int sh2 = (nh > 2) ? es[p + 2] : 0;
            G2E(sh0)
            if (nh > 1) G2E(sh1)
            if (nh > 2) G2E(sh2)
            p += nh;
        }
    }
    // main: 8 edges per iteration, two ushort4 loads, 8 gathers in flight
    for (; p + 7 < end; p += 8) {
        ushort4 eA = *(const ushort4*)(es + p);
        ushort4 eB = *(const ushort4*)(es + p + 4);
        int s0 = eA.x, s1 = eA.y, s2 = eA.z, s3 = eA.w;
        int s4 = eB.x, s5 = eB.y, s6 = eB.z, s7 = eB.w;
        float v0 = __half2float(sht[s0]), v1 = __half2float(sht[s1]);
        float v2 = __half2float(sht[s2]), v3 = __half2float(sht[s3]);
        float v4 = __half2float(sht[s4]), v5 = __half2float(sht[s5]);
        float v6 = __half2float(sht[s6]), v7 = __half2float(sht[s7]);
        float4 h0 = ldh4(h2t + (size_t)s0 * HDIM + 4 * l);
        float4 h1 = ldh4(h2t + (size_t)s1 * HDIM + 4 * l);
        float4 h2q = ldh4(h2t + (size_t)s2 * HDIM + 4 * l);
        float4 h3 = ldh4(h2t + (size_t)s3 * HDIM + 4 * l);
        float4 h4 = ldh4(h2t + (size_t)s4 * HDIM + 4 * l);
        float4 h5 = ldh4(h2t + (size_t)s5 * HDIM + 4 * l);
        float4 h6 = ldh4(h2t + (size_t)s6 * HDIM + 4 * l);
        float4 h7 = ldh4(h2t + (size_t)s7 * HDIM + 4 * l);
        float w0 = __expf(lrelu02(v0 + ad));
        float w1 = __expf(lrelu02(v1 + ad));
        float w2 = __expf(lrelu02(v2 + ad));
        float w3 = __expf(lrelu02(v3 + ad));
        float w4 = __expf(lrelu02(v4 + ad));
        float w5 = __expf(lrelu02(v5 + ad));
        float w6 = __expf(lrelu02(v6 + ad));
        float w7 = __expf(lrelu02(v7 + ad));
        acc.x = fmaf(w0, h0.x, fmaf(w1, h1.x, fmaf(w2, h2q.x, fmaf(w3, h3.x, acc.x))));
        acc.x = fmaf(w4, h4.x, fmaf(w5, h5.x, fmaf(w6, h6.x, fmaf(w7, h7.x, acc.x))));
        acc.y = fmaf(w0, h0.y, fmaf(w1, h1.y, fmaf(w2, h2q.y, fmaf(w3, h3.y, acc.y))));
        acc.y = fmaf(w4, h4.y, fmaf(w5, h5.y, fmaf(w6, h6.y, fmaf(w7, h7.y, acc.y))));
        acc.z = fmaf(w0, h0.z, fmaf(w1, h1.z, fmaf(w2, h2q.z, fmaf(w3, h3.z, acc.z))));
        acc.z = fmaf(w4, h4.z, fmaf(w5, h5.z, fmaf(w6, h6.z, fmaf(w7, h7.z, acc.z))));
        acc.w = fmaf(w0, h0.w, fmaf(w1, h1.w, fmaf(w2, h2q.w, fmaf(w3, h3.w, acc.w))));
        acc.w = fmaf(w4, h4.w, fmaf(w5, h5.w, fmaf(w6, h6.w, fmaf(w7, h7.w, acc.w))));
        den += (w0 + w1 + w2 + w3) + (w4 + w5 + w6 + w7);
    }
    // mid: 4 edges (one ushort4)
    if (p + 3 < end) {
        ushort4 eA = *(const ushort4*)(es + p);
        int s0 = eA.x, s1 = eA.y, s2 = eA.z, s3 = eA.w;
        float v0 = __half2float(sht[s0]), v1 = __half2float(sht[s1]);
        float v2 = __half2float(sht[s2]), v3 = __half2float(sht[s3]);
        float4 h0 = ldh4(h2t + (size_t)s0 * HDIM + 4 * l);
        float4 h1 = ldh4(h2t + (size_t)s1 * HDIM + 4 * l);
        float4 h2q = ldh4(h2t + (size_t)s2 * HDIM + 4 * l);
        float4 h3 = ldh4(h2t + (size_t)s3 * HDIM + 4 * l);
        float w0 = __expf(lrelu02(v0 + ad));
        float w1 = __expf(lrelu02(v1 + ad));
        float w2 = __expf(lrelu02(v2 + ad));
        float w3 = __expf(lrelu02(v3 + ad));
        acc.x = fmaf(w0, h0.x, fmaf(w1, h1.x, fmaf(w2, h2q.x, fmaf(w3, h3.x, acc.x))));
        acc.y = fmaf(w0, h0.y, fmaf(w1, h1.y, fmaf(w2, h2q.y, fmaf(w3, h3.y, acc.y))));
        acc.z = fmaf(w0, h0.z, fmaf(w1, h1.z, fmaf(w2, h2q.z, fmaf(w3, h3.z, acc.z))));
        acc.w = fmaf(w0, h0.w, fmaf(w1, h1.w, fmaf(w2, h2q.w, fmaf(w3, h3.w, acc.w))));
        den += w0 + w1 + w2 + w3;
        p += 4;
    }
    // tail: <=3 scalar (independent loads)
    {
        int nt = end - p;
        if (nt > 0) {
            int st0 = es[p];
            int st1 = (nt > 1) ? es[p + 1] : 0;
            int st2 = (nt > 2) ? es[p + 2] : 0;
            G2E(st0)
            if (nt > 1) G2E(st1)
            if (nt > 2) G2E(st2)
        }
    }
    // self-loop
    G2E(node)
#undef G2E
#undef G2W

    float invd = 1.f / (den + 1e-16f);
    float4 bb = *(const float4*)(b2 + 4 * l);
    float4 o;
    o.x = eluf(fmaf(acc.x, invd, bb.x));
    o.y = eluf(fmaf(acc.y, invd, bb.y));
    o.z = eluf(fmaf(acc.z, invd, bb.z));
    o.w = eluf(fmaf(acc.w, invd, bb.w));
    *(float4*)(z2 + (size_t)wid * HDIM + 4 * l) = o;
}

// ---- fused 8-step GRU + output projection (round-13 occupancy form) ----
#define G2_DECL(j) float air##j, aiz##j, ain##j, ahr##j, ahz##j, ahn##j, hr##j;
#define G2_ACC(j) { \
    float4 zv = *(const float4*)&zls[(nb + j) * 32 + kq]; \
    float4 hv = *(const float4*)&hls[(nb + j) * 32 + kq]; \
    air##j = fmaf(wri.w, zv.w, fmaf(wri.z, zv.z, fmaf(wri.y, zv.y, fmaf(wri.x, zv.x, air##j)))); \
    aiz##j = fmaf(wzi.w, zv.w, fmaf(wzi.z, zv.z, fmaf(wzi.y, zv.y, fmaf(wzi.x, zv.x, aiz##j)))); \
    ain##j = fmaf(wni.w, zv.w, fmaf(wni.z, zv.z, fmaf(wni.y, zv.y, fmaf(wni.x, zv.x, ain##j)))); \
    ahr##j = fmaf(wrh.w, hv.w, fmaf(wrh.z, hv.z, fmaf(wrh.y, hv.y, fmaf(wrh.x, hv.x, ahr##j)))); \
    ahz##j = fmaf(wzh.w, hv.w, fmaf(wzh.z, hv.z, fmaf(wzh.y, hv.y, fmaf(wzh.x, hv.x, ahz##j)))); \
    ahn##j = fmaf(wnh.w, hv.w, fmaf(wnh.z, hv.z, fmaf(wnh.y, hv.y, fmaf(wnh.x, hv.x, ahn##j)))); }
#define G2_FIN(j) { \
    float r = fsig(air##j + ahr##j); \
    float z = fsig(aiz##j + ahz##j); \
    float g = ftanh(ain##j + r * ahn##j); \
    hr##j = (1.f - z) * g + z * hr##j; \
    hls[(nb + j) * 32 + c] = hr##j; }

__global__ void k_gru_all(const float* __restrict__ z2, const float* __restrict__ Wih,
                          const float* __restrict__ Whh, const float* __restrict__ bih,
                          const float* __restrict__ bhh, const float* __restrict__ Wout,
                          const float* __restrict__ bout, float* __restrict__ out) {
    __shared__ float sWih[3 * HDIM * 32];  // swizzled rows, stride 32
    __shared__ float sWhh[3 * HDIM * 32];
    __shared__ float sbih[3 * HDIM], sbhh[3 * HDIM], sWout[HDIM];
    __shared__ float hls[GNB * 32];
    __shared__ float zls[GNB * 32];

    for (int i = threadIdx.x; i < 3 * HDIM * HDIM; i += 256) {
        int r = i >> 5, cc = i & 31;
        int pos = r * 32 + ((((cc >> 2) ^ (r & 7)) << 2) | (cc & 3));
        sWih[pos] = Wih[i];
        sWhh[pos] = Whh[i];
    }
    for (int i = threadIdx.x; i < 3 * HDIM; i += 256) {
        sbih[i] = bih[i];
        sbhh[i] = bhh[i];
    }
    for (int i = threadIdx.x; i < HDIM; i += 256) sWout[i] = Wout[i];
    for (int i = threadIdx.x; i < GNB * 32; i += 256) hls[i] = 0.f;
    __syncthreads();

    const int c = threadIdx.x & 31;
    const int nb = (threadIdx.x >> 5) * GNT;   // group's node base (0..14)
    const int gbase = blockIdx.x * GNB;
    const int sw = c & 7;    // row-XOR key (rows c, 32+c, 64+c share it)

    const float br = sbih[c], bz = sbih[HDIM + c], bn = sbih[2 * HDIM + c];
    const float cr = sbhh[c], cz = sbhh[HDIM + c], cn = sbhh[2 * HDIM + c];

    G2_DECL(0) G2_DECL(1)
    hr0 = hr1 = 0.f;

    for (int t = 0; t < T_STEPS; ++t) {
        // stage z2 tile (16 nodes x 32 ch = 128 float4), coalesced
        const float4* zsrc = (const float4*)(z2 + ((size_t)t * N_NODES + gbase) * HDIM);
        if (threadIdx.x < GNB * 8)
            *(float4*)&zls[threadIdx.x * 4] = zsrc[threadIdx.x];
        __syncthreads();

        air0 = air1 = br;
        aiz0 = aiz1 = bz;
        ain0 = ain1 = bn;
        ahr0 = ahr1 = cr;
        ahz0 = ahz1 = cz;
        ahn0 = ahn1 = cn;
#pragma unroll 2
        for (int q = 0; q < 8; ++q) {
            int qa = (q ^ sw) << 2;    // swizzled float-offset within row
            int kq = q << 2;           // true k position for z/h
            float4 wri = *(const float4*)&sWih[c * 32 + qa];
            float4 wzi = *(const float4*)&sWih[(HDIM + c) * 32 + qa];
            float4 wni = *(const float4*)&sWih[(2 * HDIM + c) * 32 + qa];
            float4 wrh = *(const float4*)&sWhh[c * 32 + qa];
            float4 wzh = *(const float4*)&sWhh[(HDIM + c) * 32 + qa];
            float4 wnh = *(const float4*)&sWhh[(2 * HDIM + c) * 32 + qa];
            G2_ACC(0) G2_ACC(1)
        }
        G2_FIN(0) G2_FIN(1)
        __syncthreads();  // zls reads done before next staging; hls same-wave ordered
    }

    float wo = sWout[c];
    float s0 = lane32_sum(hr0 * wo);
    float s1 = lane32_sum(hr1 * wo);
    if (c == 0) {
        float bo = bout[0];
        out[gbase + nb + 0] = s0 + bo;
        out[gbase + nb + 1] = s1 + bo;
    }
}

extern "C" void kernel_launch(void* const* d_in, const int* in_sizes, int n_in,
                              void* d_out, int out_size, void* d_ws, size_t ws_size,
                              hipStream_t stream) {
    const float* x      = (const float*)d_in[0];   // T*N
    const int* eidx     = (const int*)d_in[1];     // T*2*E
    const float* W1     = (const float*)d_in[2];
    const float* a_src1 = (const float*)d_in[3];
    const float* a_dst1 = (const float*)d_in[4];
    const float* b1     = (const float*)d_in[5];
    const float* W2     = (const float*)d_in[6];
    const float* a_src2 = (const float*)d_in[7];
    const float* a_dst2 = (const float*)d_in[8];
    const float* b2     = (const float*)d_in[9];
    const float* W_ih   = (const float*)d_in[10];
    const float* W_hh   = (const float*)d_in[11];
    const float* b_ih   = (const float*)d_in[12];
    const float* b_hh   = (const float*)d_in[13];
    const float* W_out  = (const float*)d_in[14];
    const float* b_out  = (const float*)d_in[15];
    float* out = (float*)d_out;

    char* base_ws = (char*)d_ws;
    size_t off = 0;
    auto alloc = [&](size_t bytes) {
        char* p = base_ws + off;
        off = (off + bytes + 15) & ~(size_t)15;
        return p;
    };
    int* cnt            = (int*)alloc((size_t)TN * 4);
    int* row            = (int*)alloc((size_t)(TN + 1) * 4);
    int* bsum           = (int*)alloc((size_t)SCAN_BLOCKS * 4);
    int* bpre           = (int*)alloc((size_t)SCAN_BLOCKS * 4);
    float* inv          = (float*)alloc((size_t)TN * 2 * 4);
    __half* h2h         = (__half*)alloc((size_t)TN * HDIM * 2);   // 10.24 MB
    __half* sh          = (__half*)alloc((size_t)TN * 2);          // 320 KB
    float* ad2          = (float*)alloc((size_t)TN * 4);
    float* z2           = (float*)alloc((size_t)TN * HDIM * 4);    // 20.48 MB
    float* S4           = (float*)alloc(16);
    unsigned short* es  = (unsigned short*)alloc((size_t)TE * 2);  // 10.24 MB
    // Aliases (stream-order safe):
    //  h2h region (10.24 MB) = hist8 (5.12, u8 counts) + lrow16 (5.12, u16):
    //    written by hist, read by blkpre/scatter; h2h written later by node1.
    //  z2 region (20.48 MB) = bbase (10.24) + stagedG (10.24):
    //    bbase written by blkpre, stagedG by hist; both read by scatter;
    //    z2 written later by gat2red.
    unsigned char* hist8   = (unsigned char*)h2h;
    unsigned short* lrow16 = (unsigned short*)((char*)h2h + (size_t)T_STEPS * GB * N_NODES);
    int* bbase             = (int*)z2;
    unsigned short* stagedG = (unsigned short*)((char*)z2 + (size_t)T_STEPS * GB * NPAIR * 4);

    const int B = 256;
    dim3 hgrid(GB, T_STEPS);
    k_hist<<<hgrid, 512, 0, stream>>>(eidx, hist8, lrow16, stagedG);
    k_blkpre<<<(T_STEPS * NPAIR + B - 1) / B, B, 0, stream>>>(hist8, bbase, cnt,
                                                              W1, a_src1, a_dst1, S4);
    k_scan_a<<<SCAN_BLOCKS, B, 0, stream>>>(cnt, bsum);
    k_scan_b<<<1, B, 0, stream>>>(bsum, bpre);
    k_scan_c<<<SCAN_BLOCKS, B, 0, stream>>>(cnt, bpre, row);
    k_scatter<<<8 * GB, 512, 0, stream>>>(hist8, lrow16, row, bbase, stagedG, es);

    k_gat1red<<<TN / 256, B, 0, stream>>>(es, row, x, S4, inv);
    k_node1<<<TN / NPB, B, 0, stream>>>(inv, W1, b1, W2, a_src2, a_dst2, h2h, sh, ad2);
    k_gat2red<<<TN / 8, 64, 0, stream>>>(es, row, sh, ad2, h2h, b2, z2);

    k_gru_all<<<N_NODES / GNB, B, 0, stream>>>(z2, W_ih, W_hh, b_ih, b_hh, W_out, b_out, out);
}

// Round 22
// 303.962 us; speedup vs baseline: 1.0247x; 1.0247x over previous
//
#include <hip/hip_runtime.h>
#include <hip/hip_fp16.h>
#include <math.h>

#define N_NODES 20000
#define T_STEPS 8
#define E_EDGES 640000
#define TN (T_STEPS * N_NODES)   // 160000
#define TE (T_STEPS * E_EDGES)   // 5120000
#define HDIM 32
#define HEADS 2
#define NPB 8                    // nodes per block for lane-parallel node kernels
#define SCAN_BLOCKS 625          // TN / 256 exactly
#define GB 32                    // histogram blocks per timestep
#define CHUNK (E_EDGES / GB)     // 20000 edges per histogram block
#define NPAIR (N_NODES / 2)      // packed bins per timestep
#define GNT 2                    // GRU nodes per thread-group (occupancy lever)
#define GNB (8 * GNT)            // GRU nodes per block = 16 (1250 blocks exactly)

__device__ __forceinline__ float lrelu02(float v) { return fmaxf(v, 0.2f * v); }
__device__ __forceinline__ float eluf(float v) { return v > 0.f ? v : expm1f(v); }
__device__ __forceinline__ float fsig(float v) {
    return __fdividef(1.f, 1.f + __expf(-v));
}
__device__ __forceinline__ float ftanh(float v) {
    return 1.f - __fdividef(2.f, __expf(2.f * v) + 1.f);
}

__device__ __forceinline__ float lane32_sum(float v) {
    v += __shfl_xor(v, 16);
    v += __shfl_xor(v, 8);
    v += __shfl_xor(v, 4);
    v += __shfl_xor(v, 2);
    v += __shfl_xor(v, 1);
    return v;
}

// load 4 fp16 channels (8 B, one dword2) -> float4
__device__ __forceinline__ float4 ldh4(const __half* p) {
    uint2 u = *(const uint2*)p;
    __half2 a = *(__half2*)&u.x;
    __half2 b = *(__half2*)&u.y;
    float2 f0 = __half22float2(a);
    float2 f1 = __half22float2(b);
    return make_float4(f0.x, f0.y, f1.x, f1.y);
}

// ---- pass A: per-block LDS histogram + local scan + locally-sorted staging.
// 1024 threads (4 waves/SIMD), src/dst cached in LDS u16 (one ei pass),
// 1-D grid with t = blockIdx.x & 7 (XCD-pinned outputs).
// ROUND-21 BUG FIX: __syncthreads() between the lrow16 write (reads lh) and
// the staged fill (atomicAdds lh). The race was latent in round 20 (masked
// by slow global loads in the staged loop) and exposed by the LDS cache.
__global__ void k_hist(const int* __restrict__ ei, unsigned char* __restrict__ hist8,
                       unsigned short* __restrict__ lrow16,
                       unsigned short* __restrict__ stagedG) {
    __shared__ int lh[NPAIR];                 // 40 KB: counts -> packed lrow
    __shared__ unsigned short sdst[CHUNK];    // 40 KB
    __shared__ unsigned short ssrc[CHUNK];    // 40 KB
    __shared__ int partial[1024];             // 4 KB
    int t = blockIdx.x & 7, b = blockIdx.x >> 3;
    for (int i = threadIdx.x; i < NPAIR; i += 1024) lh[i] = 0;
    __syncthreads();
    const int* srcp = ei + (size_t)t * 2 * E_EDGES + b * CHUNK;
    const int* dstp = srcp + E_EDGES;
    for (int j = threadIdx.x; j < CHUNK; j += 1024) {
        int dst = dstp[j];
        int src = srcp[j];
        sdst[j] = (unsigned short)dst;
        ssrc[j] = (unsigned short)src;
        atomicAdd(&lh[dst >> 1], (dst & 1) ? 65536 : 1);
    }
    __syncthreads();
    size_t bi = (size_t)t * GB + b;
    // write u8 counts (max per-block bin ~12)
    unsigned char* hp = hist8 + bi * N_NODES;
    for (int i = threadIdx.x; i < NPAIR; i += 1024) {
        int v = lh[i];
        uchar2 pk;
        pk.x = (unsigned char)(v & 0xff);
        pk.y = (unsigned char)((v >> 16) & 0xff);
        *(uchar2*)(hp + 2 * i) = pk;
    }
    __syncthreads();
    // exclusive scan over interleaved (low,high) counts; 10 pairs/thread
    const int tpp = 10;   // 1024*10 >= NPAIR
    int i0 = threadIdx.x * tpp;
    int run = 0;
    for (int k = 0; k < tpp; ++k) {
        int i = i0 + k;
        if (i < NPAIR) {
            int v = lh[i];
            run += (v & 0xffff) + (v >> 16);
        }
    }
    partial[threadIdx.x] = run;
    __syncthreads();
    for (int off = 1; off < 1024; off <<= 1) {
        int add = (threadIdx.x >= off) ? partial[threadIdx.x - off] : 0;
        __syncthreads();
        partial[threadIdx.x] += add;
        __syncthreads();
    }
    int run2 = (threadIdx.x > 0) ? partial[threadIdx.x - 1] : 0;
    for (int k = 0; k < tpp; ++k) {
        int i = i0 + k;
        if (i < NPAIR) {
            int v = lh[i];
            int c0 = v & 0xffff, c1 = v >> 16;
            lh[i] = run2 | ((run2 + c0) << 16);   // packed (l0, l1)
            run2 += c0 + c1;
        }
    }
    __syncthreads();
    // write l0 only (l1 = l0 + c0 derivable in scatter)
    unsigned short* lp = lrow16 + bi * NPAIR;
    for (int i = threadIdx.x; i < NPAIR; i += 1024)
        lp[i] = (unsigned short)(lh[i] & 0xffff);
    __syncthreads();   // <<< FIX: all lrow reads of lh done before atomics mutate lh
    // fill staged window from LDS-cached edges (no global reads; private
    // 40 KB window in L2, written back once)
    unsigned short* stg = stagedG + bi * CHUNK;
    for (int j = threadIdx.x; j < CHUNK; j += 1024) {
        int dst = sdst[j];
        int old = atomicAdd(&lh[dst >> 1], (dst & 1) ? 65536 : 1);
        int pos = (old >> (16 * (dst & 1))) & 0xffff;
        stg[pos] = ssrc[j];
    }
}

// ---- pass B: per-(t,dst) prefix over blocks -> base (packed) + totals.
// Thread (0,0) also does the tiny GAT1 rank-1 prep (folds k_prep launch).
__global__ void k_blkpre(const unsigned char* __restrict__ hist8, int* __restrict__ base,
                         int* __restrict__ cnt, const float* __restrict__ W1,
                         const float* __restrict__ as1, const float* __restrict__ ad1,
                         float* __restrict__ S4) {
    int i = blockIdx.x * blockDim.x + threadIdx.x;  // (t, pair)
    if (i == 0) {
        for (int hd = 0; hd < HEADS; ++hd) {
            float ss = 0.f, sd = 0.f;
            for (int c = 0; c < HDIM; ++c) {
                ss += W1[hd * HDIM + c] * as1[hd * HDIM + c];
                sd += W1[hd * HDIM + c] * ad1[hd * HDIM + c];
            }
            S4[hd] = ss;
            S4[HEADS + hd] = sd;
        }
    }
    if (i >= T_STEPS * NPAIR) return;
    int t = i / NPAIR, pr = i % NPAIR;
    int a0 = 0, a1 = 0;
    for (int b = 0; b < GB; ++b) {
        size_t bi = ((size_t)t * GB + b);
        uchar2 v = *(const uchar2*)(hist8 + bi * N_NODES + 2 * pr);
        base[bi * NPAIR + pr] = a0 | (a1 << 16);
        a0 += v.x;
        a1 += v.y;
    }
    cnt[t * N_NODES + 2 * pr] = a0;
    cnt[t * N_NODES + 2 * pr + 1] = a1;
}

// ---- scan (exclusive) over cnt[TN] -> row[TN+1] ----
__global__ void k_scan_a(const int* __restrict__ cnt, int* __restrict__ bsum) {
    __shared__ int s[256];
    int i = blockIdx.x * 256 + threadIdx.x;
    s[threadIdx.x] = (i < TN) ? cnt[i] : 0;
    __syncthreads();
    for (int off = 128; off > 0; off >>= 1) {
        if (threadIdx.x < off) s[threadIdx.x] += s[threadIdx.x + off];
        __syncthreads();
    }
    if (threadIdx.x == 0) bsum[blockIdx.x] = s[0];
}

__global__ void k_scan_b(const int* __restrict__ bsum, int* __restrict__ bpre) {
    __shared__ int s[256];
    __shared__ int carry;
    if (threadIdx.x == 0) carry = 0;
    __syncthreads();
    for (int base = 0; base < SCAN_BLOCKS; base += 256) {
        int i = base + threadIdx.x;
        int v = (i < SCAN_BLOCKS) ? bsum[i] : 0;
        s[threadIdx.x] = v;
        __syncthreads();
        for (int off = 1; off < 256; off <<= 1) {
            int add = (threadIdx.x >= off) ? s[threadIdx.x - off] : 0;
            __syncthreads();
            s[threadIdx.x] += add;
            __syncthreads();
        }
        if (i < SCAN_BLOCKS) bpre[i] = carry + s[threadIdx.x] - v;  // exclusive
        __syncthreads();
        if (threadIdx.x == 0) carry += s[255];
        __syncthreads();
    }
}

__global__ void k_scan_c(const int* __restrict__ cnt, const int* __restrict__ bpre,
                         int* __restrict__ row) {
    __shared__ int s[256];
    int i = blockIdx.x * 256 + threadIdx.x;
    int v = (i < TN) ? cnt[i] : 0;
    s[threadIdx.x] = v;
    __syncthreads();
    for (int off = 1; off < 256; off <<= 1) {
        int add = (threadIdx.x >= off) ? s[threadIdx.x - off] : 0;
        __syncthreads();
        s[threadIdx.x] += add;
        __syncthreads();
    }
    if (i < TN) row[i] = bpre[blockIdx.x] + s[threadIdx.x] - v;
    if (blockIdx.x == 0 && threadIdx.x == 0) row[TN] = TE;
}

// ---- pass C: per-bin copy from locally-sorted staging into global CSR.
// All blocks of a timestep sweep dst in increasing order -> es stores are a
// monotone sweep, lines filled by temporally-adjacent stores (no churn).
// XCD-pinned per timestep (t = blockIdx.x & 7).
__global__ void k_scatter(const unsigned char* __restrict__ hist8,
                          const unsigned short* __restrict__ lrow16,
                          const int* __restrict__ row, const int* __restrict__ base,
                          const unsigned short* __restrict__ stagedG,
                          unsigned short* __restrict__ es) {
    int t = blockIdx.x & 7;
    int b = blockIdx.x >> 3;          // 0..31
    size_t bi = (size_t)t * GB + b;
    const unsigned char* h8 = hist8 + bi * N_NODES;
    const unsigned short* lr = lrow16 + bi * NPAIR;
    const int* bs = base + bi * NPAIR;
    const unsigned short* stg = stagedG + bi * CHUNK;
    const int* rw = row + t * N_NODES;
    for (int i = threadIdx.x; i < NPAIR; i += blockDim.x) {
        uchar2 c = *(const uchar2*)(h8 + 2 * i);
        int l0 = lr[i];
        int l1 = l0 + c.x;
        int bp = bs[i];
        int b0 = bp & 0xffff, b1 = (bp >> 16) & 0xffff;
        int2 rr = *(const int2*)(rw + 2 * i);
        for (int k = 0; k < c.x; ++k) es[rr.x + b0 + k] = stg[l0 + k];
        for (int k = 0; k < c.y; ++k) es[rr.y + b1 + k] = stg[l1 + k];
    }
}

// ---- GAT1 reduce: ONE THREAD per (t,dst) bin; ushort4 es loads + unroll-4 ----
__global__ void k_gat1red(const unsigned short* __restrict__ es, const int* __restrict__ row,
                          const float* __restrict__ x, const float* __restrict__ S4,
                          float* __restrict__ inv) {
    int wid = blockIdx.x * 256 + threadIdx.x;  // grid exact: 625*256 == TN
    int t = wid / N_NODES;
    int start = row[wid], end = row[wid + 1];
    float Ss0 = S4[0], Ss1 = S4[1], Sd0 = S4[2], Sd1 = S4[3];
    float xd = x[wid];
    float a0 = xd * Sd0, a1 = xd * Sd1;
    const float* xt = x + (size_t)t * N_NODES;
    // self-loop init
    float w0 = __expf(lrelu02(fmaf(xd, Ss0, a0))), w1 = __expf(lrelu02(fmaf(xd, Ss1, a1)));
    float d0 = w0, n0 = w0 * xd, d1 = w1, n1 = w1 * xd;

#define G1E(xs) { \
    float v0 = __expf(lrelu02(fmaf(xs, Ss0, a0))); \
    float v1 = __expf(lrelu02(fmaf(xs, Ss1, a1))); \
    d0 += v0; n0 = fmaf(v0, xs, n0); \
    d1 += v1; n1 = fmaf(v1, xs, n1); }

    int p = start;
    // head: align to 4
    {
        int nh = (4 - (start & 3)) & 3;
        if (nh > end - start) nh = end - start;
        if (nh > 0) {
            float xa = xt[es[p]];
            float xb = (nh > 1) ? xt[es[p + 1]] : 0.f;
            float xc = (nh > 2) ? xt[es[p + 2]] : 0.f;
            G1E(xa)
            if (nh > 1) G1E(xb)
            if (nh > 2) G1E(xc)
            p += nh;
        }
    }
    for (; p + 3 < end; p += 4) {
        ushort4 e4 = *(const ushort4*)(es + p);
        float xa = xt[e4.x], xb = xt[e4.y], xc = xt[e4.z], xe = xt[e4.w];
        float va0 = __expf(lrelu02(fmaf(xa, Ss0, a0)));
        float va1 = __expf(lrelu02(fmaf(xa, Ss1, a1)));
        float vb0 = __expf(lrelu02(fmaf(xb, Ss0, a0)));
        float vb1 = __expf(lrelu02(fmaf(xb, Ss1, a1)));
        float vc0 = __expf(lrelu02(fmaf(xc, Ss0, a0)));
        float vc1 = __expf(lrelu02(fmaf(xc, Ss1, a1)));
        float ve0 = __expf(lrelu02(fmaf(xe, Ss0, a0)));
        float ve1 = __expf(lrelu02(fmaf(xe, Ss1, a1)));
        d0 += va0 + vb0 + vc0 + ve0;
        d1 += va1 + vb1 + vc1 + ve1;
        n0 = fmaf(va0, xa, fmaf(vb0, xb, fmaf(vc0, xc, fmaf(ve0, xe, n0))));
        n1 = fmaf(va1, xa, fmaf(vb1, xb, fmaf(vc1, xc, fmaf(ve1, xe, n1))));
    }
    {
        int nt = end - p;
        if (nt > 0) {
            float xa = xt[es[p]];
            float xb = (nt > 1) ? xt[es[p + 1]] : 0.f;
            float xc = (nt > 2) ? xt[es[p + 2]] : 0.f;
            G1E(xa)
            if (nt > 1) G1E(xb)
            if (nt > 2) G1E(xc)
        }
    }
#undef G1E
    inv[(size_t)wid * 2 + 0] = n0 / (d0 + 1e-16f);
    inv[(size_t)wid * 2 + 1] = n1 / (d1 + 1e-16f);
}

// ---- GAT1 epilogue + h2 = elu(z1) @ W2 (stored FP16: 64B row = 1 cache line)
// + src-logit as2 stored FP16 (40KB/t table: L1-resident in gat2red).
__global__ void k_node1(const float* __restrict__ inv, const float* __restrict__ W1,
                        const float* __restrict__ b1, const float* __restrict__ W2,
                        const float* __restrict__ as2w, const float* __restrict__ ad2w,
                        __half* __restrict__ h2h, __half* __restrict__ sh,
                        float* __restrict__ ad2) {
    __shared__ float sW1[HEADS * HDIM];
    __shared__ float sb1[HEADS * HDIM];
    __shared__ float sW2[HEADS * HDIM * (HDIM + 1)];
    __shared__ float sas[HDIM], sad[HDIM];
    __shared__ float z1s[NPB][HEADS * HDIM + 1];

    for (int i = threadIdx.x; i < HEADS * HDIM; i += blockDim.x) {
        sW1[i] = W1[i];
        sb1[i] = b1[i];
    }
    for (int i = threadIdx.x; i < HEADS * HDIM * HDIM; i += blockDim.x) {
        int k = i >> 5, c = i & 31;
        sW2[k * (HDIM + 1) + c] = W2[i];
    }
    for (int i = threadIdx.x; i < HDIM; i += blockDim.x) {
        sas[i] = as2w[i];
        sad[i] = ad2w[i];
    }
    __syncthreads();

    int ln = threadIdx.x >> 5;
    int c = threadIdx.x & 31;
    int tn = blockIdx.x * NPB + ln;
    if (tn >= TN) return;

    float inv0 = inv[(size_t)tn * 2 + 0];
    float inv1 = inv[(size_t)tn * 2 + 1];
    z1s[ln][c] = eluf(inv0 * sW1[c] + sb1[c]);
    z1s[ln][HDIM + c] = eluf(inv1 * sW1[HDIM + c] + sb1[HDIM + c]);
    __syncthreads();

    float acc = 0.f;
#pragma unroll
    for (int k = 0; k < HEADS * HDIM; ++k)
        acc += z1s[ln][k] * sW2[k * (HDIM + 1) + c];

    h2h[(size_t)tn * HDIM + c] = __float2half_rn(acc);
    float s = lane32_sum(acc * sas[c]);
    float d = lane32_sum(acc * sad[c]);
    if (c == 0) {
        sh[tn] = __float2half_rn(s);   // src logit (fp16)
        ad2[tn] = d;
    }
}

// ---- GAT2 reduce: ONE WAVE per block (8 nodes x 8 channel-quads).
// Per edge: 1 fp16 logit (L1-resident 40KB table) + 1 h2 line. Direct
// w = __expf(lrelu(sv+ad)) — trans pipe idle, no eab L2 gather.
__global__ void k_gat2red(const unsigned short* __restrict__ es, const int* __restrict__ row,
                          const __half* __restrict__ sh, const float* __restrict__ ad2,
                          const __half* __restrict__ h2h, const float* __restrict__ b2,
                          float* __restrict__ z2) {
    int b = blockIdx.x;
    int t = b & 7;            // XCD pin: blocks on one XCD share one timestep
    int chunk = b >> 3;       // 0..2499
    int lane = threadIdx.x;   // block = 64 threads = 1 wave
    int u = lane >> 3;        // node slot 0..7
    int l = lane & 7;         // channel quad: channels 4l..4l+3
    int node = chunk * 8 + u; // exact: 2500*8 == 20000
    int wid = t * N_NODES + node;

    int start = row[wid], end = row[wid + 1];
    float ad = ad2[wid];
    const __half* sht = sh + (size_t)t * N_NODES;
    const __half* h2t = h2h + (size_t)t * N_NODES * HDIM;

    float4 acc = make_float4(0.f, 0.f, 0.f, 0.f);
    float den = 0.f;

#define G2W(sv) __expf(lrelu02(__half2float(sht[sv]) + ad))
#define G2E(sv) { \
    float w = G2W(sv); \
    float4 hv = ldh4(h2t + (size_t)(sv) * HDIM + 4 * l); \
    acc.x = fmaf(w, hv.x, acc.x); \
    acc.y = fmaf(w, hv.y, acc.y); \
    acc.z = fmaf(w, hv.z, acc.z); \
    acc.w = fmaf(w, hv.w, acc.w); \
    den += w; }

    int p = start;
    // head: align p to 4 (<=3 edges; independent scalar loads)
    {
        int nh = (4 - (start & 3)) & 3;
        if (nh > end - start) nh = end - start;
        if (nh > 0) {
            int sh0 = es[p];
            int sh1 = (nh > 1) ? es[p + 1] : 0;
            int sh2 = (nh > 2) ? es[p + 2] : 0;
            G2E(sh0)
            if (nh > 1) G2E(sh1)
            if (nh > 2) G2E(sh2)
            p += nh;
        }
    }
    // main: 8 edges per iteration, two ushort4 loads, 8 gathers in flight
    for (; p + 7 < end; p += 8) {
        ushort4 eA = *(const ushort4*)(es + p);
        ushort4 eB = *(const ushort4*)(es + p + 4);
        int s0 = eA.x, s1 = eA.y, s2 = eA.z, s3 = eA.w;
        int s4 = eB.x, s5 = eB.y, s6 = eB.z, s7 = eB.w;
        float v0 = __half2float(sht[s0]), v1 = __half2float(sht[s1]);
        float v2 = __half2float(sht[s2]), v3 = __half2float(sht[s3]);
        float v4 = __half2float(sht[s4]), v5 = __half2float(sht[s5]);
        float v6 = __half2float(sht[s6]), v7 = __half2float(sht[s7]);
        float4 h0 = ldh4(h2t + (size_t)s0 * HDIM + 4 * l);
        float4 h1 = ldh4(h2t + (size_t)s1 * HDIM + 4 * l);
        float4 h2q = ldh4(h2t + (size_t)s2 * HDIM + 4 * l);
        float4 h3 = ldh4(h2t + (size_t)s3 * HDIM + 4 * l);
        float4 h4 = ldh4(h2t + (size_t)s4 * HDIM + 4 * l);
        float4 h5 = ldh4(h2t + (size_t)s5 * HDIM + 4 * l);
        float4 h6 = ldh4(h2t + (size_t)s6 * HDIM + 4 * l);
        float4 h7 = ldh4(h2t + (size_t)s7 * HDIM + 4 * l);
        float w0 = __expf(lrelu02(v0 + ad));
        float w1 = __expf(lrelu02(v1 + ad));
        float w2 = __expf(lrelu02(v2 + ad));
        float w3 = __expf(lrelu02(v3 + ad));
        float w4 = __expf(lrelu02(v4 + ad));
        float w5 = __expf(lrelu02(v5 + ad));
        float w6 = __expf(lrelu02(v6 + ad));
        float w7 = __expf(lrelu02(v7 + ad));
        acc.x = fmaf(w0, h0.x, fmaf(w1, h1.x, fmaf(w2, h2q.x, fmaf(w3, h3.x, acc.x))));
        acc.x = fmaf(w4, h4.x, fmaf(w5, h5.x, fmaf(w6, h6.x, fmaf(w7, h7.x, acc.x))));
        acc.y = fmaf(w0, h0.y, fmaf(w1, h1.y, fmaf(w2, h2q.y, fmaf(w3, h3.y, acc.y))));
        acc.y = fmaf(w4, h4.y, fmaf(w5, h5.y, fmaf(w6, h6.y, fmaf(w7, h7.y, acc.y))));
        acc.z = fmaf(w0, h0.z, fmaf(w1, h1.z, fmaf(w2, h2q.z, fmaf(w3, h3.z, acc.z))));
        acc.z = fmaf(w4, h4.z, fmaf(w5, h5.z, fmaf(w6, h6.z, fmaf(w7, h7.z, acc.z))));
        acc.w = fmaf(w0, h0.w, fmaf(w1, h1.w, fmaf(w2, h2q.w, fmaf(w3, h3.w, acc.w))));
        acc.w = fmaf(w4, h4.w, fmaf(w5, h5.w, fmaf(w6, h6.w, fmaf(w7, h7.w, acc.w))));
        den += (w0 + w1 + w2 + w3) + (w4 + w5 + w6 + w7);
    }
    // mid: 4 edges (one ushort4)
    if (p + 3 < end) {
        ushort4 eA = *(const ushort4*)(es + p);
        int s0 = eA.x, s1 = eA.y, s2 = eA.z, s3 = eA.w;
        float v0 = __half2float(sht[s0]), v1 = __half2float(sht[s1]);
        float v2 = __half2float(sht[s2]), v3 = __half2float(sht[s3]);
        float4 h0 = ldh4(h2t + (size_t)s0 * HDIM + 4 * l);
        float4 h1 = ldh4(h2t + (size_t)s1 * HDIM + 4 * l);
        float4 h2q = ldh4(h2t + (size_t)s2 * HDIM + 4 * l);
        float4 h3 = ldh4(h2t + (size_t)s3 * HDIM + 4 * l);
        float w0 = __expf(lrelu02(v0 + ad));
        float w1 = __expf(lrelu02(v1 + ad));
        float w2 = __expf(lrelu02(v2 + ad));
        float w3 = __expf(lrelu02(v3 + ad));
        acc.x = fmaf(w0, h0.x, fmaf(w1, h1.x, fmaf(w2, h2q.x, fmaf(w3, h3.x, acc.x))));
        acc.y = fmaf(w0, h0.y, fmaf(w1, h1.y, fmaf(w2, h2q.y, fmaf(w3, h3.y, acc.y))));
        acc.z = fmaf(w0, h0.z, fmaf(w1, h1.z, fmaf(w2, h2q.z, fmaf(w3, h3.z, acc.z))));
        acc.w = fmaf(w0, h0.w, fmaf(w1, h1.w, fmaf(w2, h2q.w, fmaf(w3, h3.w, acc.w))));
        den += w0 + w1 + w2 + w3;
        p += 4;
    }
    // tail: <=3 scalar (independent loads)
    {
        int nt = end - p;
        if (nt > 0) {
            int st0 = es[p];
            int st1 = (nt > 1) ? es[p + 1] : 0;
            int st2 = (nt > 2) ? es[p + 2] : 0;
            G2E(st0)
            if (nt > 1) G2E(st1)
            if (nt > 2) G2E(st2)
        }
    }
    // self-loop
    G2E(node)
#undef G2E
#undef G2W

    float invd = 1.f / (den + 1e-16f);
    float4 bb = *(const float4*)(b2 + 4 * l);
    float4 o;
    o.x = eluf(fmaf(acc.x, invd, bb.x));
    o.y = eluf(fmaf(acc.y, invd, bb.y));
    o.z = eluf(fmaf(acc.z, invd, bb.z));
    o.w = eluf(fmaf(acc.w, invd, bb.w));
    *(float4*)(z2 + (size_t)wid * HDIM + 4 * l) = o;
}

// ---- fused 8-step GRU + output projection (round-13 occupancy form) ----
#define G2_DECL(j) float air##j, aiz##j, ain##j, ahr##j, ahz##j, ahn##j, hr##j;
#define G2_ACC(j) { \
    float4 zv = *(const float4*)&zls[(nb + j) * 32 + kq]; \
    float4 hv = *(const float4*)&hls[(nb + j) * 32 + kq]; \
    air##j = fmaf(wri.w, zv.w, fmaf(wri.z, zv.z, fmaf(wri.y, zv.y, fmaf(wri.x, zv.x, air##j)))); \
    aiz##j = fmaf(wzi.w, zv.w, fmaf(wzi.z, zv.z, fmaf(wzi.y, zv.y, fmaf(wzi.x, zv.x, aiz##j)))); \
    ain##j = fmaf(wni.w, zv.w, fmaf(wni.z, zv.z, fmaf(wni.y, zv.y, fmaf(wni.x, zv.x, ain##j)))); \
    ahr##j = fmaf(wrh.w, hv.w, fmaf(wrh.z, hv.z, fmaf(wrh.y, hv.y, fmaf(wrh.x, hv.x, ahr##j)))); \
    ahz##j = fmaf(wzh.w, hv.w, fmaf(wzh.z, hv.z, fmaf(wzh.y, hv.y, fmaf(wzh.x, hv.x, ahz##j)))); \
    ahn##j = fmaf(wnh.w, hv.w, fmaf(wnh.z, hv.z, fmaf(wnh.y, hv.y, fmaf(wnh.x, hv.x, ahn##j)))); }
#define G2_FIN(j) { \
    float r = fsig(air##j + ahr##j); \
    float z = fsig(aiz##j + ahz##j); \
    float g = ftanh(ain##j + r * ahn##j); \
    hr##j = (1.f - z) * g + z * hr##j; \
    hls[(nb + j) * 32 + c] = hr##j; }

__global__ void k_gru_all(const float* __restrict__ z2, const float* __restrict__ Wih,
                          const float* __restrict__ Whh, const float* __restrict__ bih,
                          const float* __restrict__ bhh, const float* __restrict__ Wout,
                          const float* __restrict__ bout, float* __restrict__ out) {
    __shared__ float sWih[3 * HDIM * 32];  // swizzled rows, stride 32
    __shared__ float sWhh[3 * HDIM * 32];
    __shared__ float sbih[3 * HDIM], sbhh[3 * HDIM], sWout[HDIM];
    __shared__ float hls[GNB * 32];
    __shared__ float zls[GNB * 32];

    for (int i = threadIdx.x; i < 3 * HDIM * HDIM; i += 256) {
        int r = i >> 5, cc = i & 31;
        int pos = r * 32 + ((((cc >> 2) ^ (r & 7)) << 2) | (cc & 3));
        sWih[pos] = Wih[i];
        sWhh[pos] = Whh[i];
    }
    for (int i = threadIdx.x; i < 3 * HDIM; i += 256) {
        sbih[i] = bih[i];
        sbhh[i] = bhh[i];
    }
    for (int i = threadIdx.x; i < HDIM; i += 256) sWout[i] = Wout[i];
    for (int i = threadIdx.x; i < GNB * 32; i += 256) hls[i] = 0.f;
    __syncthreads();

    const int c = threadIdx.x & 31;
    const int nb = (threadIdx.x >> 5) * GNT;   // group's node base (0..14)
    const int gbase = blockIdx.x * GNB;
    const int sw = c & 7;    // row-XOR key (rows c, 32+c, 64+c share it)

    const float br = sbih[c], bz = sbih[HDIM + c], bn = sbih[2 * HDIM + c];
    const float cr = sbhh[c], cz = sbhh[HDIM + c], cn = sbhh[2 * HDIM + c];

    G2_DECL(0) G2_DECL(1)
    hr0 = hr1 = 0.f;

    for (int t = 0; t < T_STEPS; ++t) {
        // stage z2 tile (16 nodes x 32 ch = 128 float4), coalesced
        const float4* zsrc = (const float4*)(z2 + ((size_t)t * N_NODES + gbase) * HDIM);
        if (threadIdx.x < GNB * 8)
            *(float4*)&zls[threadIdx.x * 4] = zsrc[threadIdx.x];
        __syncthreads();

        air0 = air1 = br;
        aiz0 = aiz1 = bz;
        ain0 = ain1 = bn;
        ahr0 = ahr1 = cr;
        ahz0 = ahz1 = cz;
        ahn0 = ahn1 = cn;
#pragma unroll 2
        for (int q = 0; q < 8; ++q) {
            int qa = (q ^ sw) << 2;    // swizzled float-offset within row
            int kq = q << 2;           // true k position for z/h
            float4 wri = *(const float4*)&sWih[c * 32 + qa];
            float4 wzi = *(const float4*)&sWih[(HDIM + c) * 32 + qa];
            float4 wni = *(const float4*)&sWih[(2 * HDIM + c) * 32 + qa];
            float4 wrh = *(const float4*)&sWhh[c * 32 + qa];
            float4 wzh = *(const float4*)&sWhh[(HDIM + c) * 32 + qa];
            float4 wnh = *(const float4*)&sWhh[(2 * HDIM + c) * 32 + qa];
            G2_ACC(0) G2_ACC(1)
        }
        G2_FIN(0) G2_FIN(1)
        __syncthreads();  // zls reads done before next staging; hls same-wave ordered
    }

    float wo = sWout[c];
    float s0 = lane32_sum(hr0 * wo);
    float s1 = lane32_sum(hr1 * wo);
    if (c == 0) {
        float bo = bout[0];
        out[gbase + nb + 0] = s0 + bo;
        out[gbase + nb + 1] = s1 + bo;
    }
}

extern "C" void kernel_launch(void* const* d_in, const int* in_sizes, int n_in,
                              void* d_out, int out_size, void* d_ws, size_t ws_size,
                              hipStream_t stream) {
    const float* x      = (const float*)d_in[0];   // T*N
    const int* eidx     = (const int*)d_in[1];     // T*2*E
    const float* W1     = (const float*)d_in[2];
    const float* a_src1 = (const float*)d_in[3];
    const float* a_dst1 = (const float*)d_in[4];
    const float* b1     = (const float*)d_in[5];
    const float* W2     = (const float*)d_in[6];
    const float* a_src2 = (const float*)d_in[7];
    const float* a_dst2 = (const float*)d_in[8];
    const float* b2     = (const float*)d_in[9];
    const float* W_ih   = (const float*)d_in[10];
    const float* W_hh   = (const float*)d_in[11];
    const float* b_ih   = (const float*)d_in[12];
    const float* b_hh   = (const float*)d_in[13];
    const float* W_out  = (const float*)d_in[14];
    const float* b_out  = (const float*)d_in[15];
    float* out = (float*)d_out;

    char* base_ws = (char*)d_ws;
    size_t off = 0;
    auto alloc = [&](size_t bytes) {
        char* p = base_ws + off;
        off = (off + bytes + 15) & ~(size_t)15;
        return p;
    };
    int* cnt            = (int*)alloc((size_t)TN * 4);
    int* row            = (int*)alloc((size_t)(TN + 1) * 4);
    int* bsum           = (int*)alloc((size_t)SCAN_BLOCKS * 4);
    int* bpre           = (int*)alloc((size_t)SCAN_BLOCKS * 4);
    float* inv          = (float*)alloc((size_t)TN * 2 * 4);
    __half* h2h         = (__half*)alloc((size_t)TN * HDIM * 2);   // 10.24 MB
    __half* sh          = (__half*)alloc((size_t)TN * 2);          // 320 KB
    float* ad2          = (float*)alloc((size_t)TN * 4);
    float* z2           = (float*)alloc((size_t)TN * HDIM * 4);    // 20.48 MB
    float* S4           = (float*)alloc(16);
    unsigned short* es  = (unsigned short*)alloc((size_t)TE * 2);  // 10.24 MB
    // Aliases (stream-order safe):
    //  h2h region (10.24 MB) = hist8 (5.12, u8 counts) + lrow16 (5.12, u16):
    //    written by hist, read by blkpre/scatter; h2h written later by node1.
    //  z2 region (20.48 MB) = bbase (10.24) + stagedG (10.24):
    //    bbase written by blkpre, stagedG by hist; both read by scatter;
    //    z2 written later by gat2red.
    unsigned char* hist8   = (unsigned char*)h2h;
    unsigned short* lrow16 = (unsigned short*)((char*)h2h + (size_t)T_STEPS * GB * N_NODES);
    int* bbase             = (int*)z2;
    unsigned short* stagedG = (unsigned short*)((char*)z2 + (size_t)T_STEPS * GB * NPAIR * 4);

    const int B = 256;
    k_hist<<<8 * GB, 1024, 0, stream>>>(eidx, hist8, lrow16, stagedG);
    k_blkpre<<<(T_STEPS * NPAIR + B - 1) / B, B, 0, stream>>>(hist8, bbase, cnt,
                                                              W1, a_src1, a_dst1, S4);
    k_scan_a<<<SCAN_BLOCKS, B, 0, stream>>>(cnt, bsum);
    k_scan_b<<<1, B, 0, stream>>>(bsum, bpre);
    k_scan_c<<<SCAN_BLOCKS, B, 0, stream>>>(cnt, bpre, row);
    k_scatter<<<8 * GB, 512, 0, stream>>>(hist8, lrow16, row, bbase, stagedG, es);

    k_gat1red<<<TN / 256, B, 0, stream>>>(es, row, x, S4, inv);
    k_node1<<<TN / NPB, B, 0, stream>>>(inv, W1, b1, W2, a_src2, a_dst2, h2h, sh, ad2);
    k_gat2red<<<TN / 8, 64, 0, stream>>>(es, row, sh, ad2, h2h, b2, z2);

    k_gru_all<<<N_NODES / GNB, B, 0, stream>>>(z2, W_ih, W_hh, b_ih, b_hh, W_out, b_out, out);
}

// Round 23
// 286.258 us; speedup vs baseline: 1.0881x; 1.0618x over previous
//
#include <hip/hip_runtime.h>
#include <hip/hip_fp16.h>
#include <math.h>

#define N_NODES 20000
#define T_STEPS 8
#define E_EDGES 640000
#define TN (T_STEPS * N_NODES)   // 160000
#define TE (T_STEPS * E_EDGES)   // 5120000
#define HDIM 32
#define HEADS 2
#define NPB 8                    // nodes per block for lane-parallel node kernels
#define SCAN_BLOCKS 625          // TN / 256 exactly
#define GB 32                    // histogram blocks per timestep
#define CHUNK (E_EDGES / GB)     // 20000 edges per histogram block
#define NPAIR (N_NODES / 2)      // packed bins per timestep
#define GNT 2                    // GRU nodes per thread-group
#define GNB (8 * GNT)            // GRU nodes per block = 16 (1250 blocks exactly)

typedef _Float16 h2v __attribute__((ext_vector_type(2)));

__device__ __forceinline__ float lrelu02(float v) { return fmaxf(v, 0.2f * v); }
__device__ __forceinline__ float eluf(float v) { return v > 0.f ? v : expm1f(v); }
__device__ __forceinline__ float fsig(float v) {
    return __fdividef(1.f, 1.f + __expf(-v));
}
__device__ __forceinline__ float ftanh(float v) {
    return 1.f - __fdividef(2.f, __expf(2.f * v) + 1.f);
}

__device__ __forceinline__ float lane32_sum(float v) {
    v += __shfl_xor(v, 16);
    v += __shfl_xor(v, 8);
    v += __shfl_xor(v, 4);
    v += __shfl_xor(v, 2);
    v += __shfl_xor(v, 1);
    return v;
}

// load 4 fp16 channels (8 B, one dword2) -> float4
__device__ __forceinline__ float4 ldh4(const __half* p) {
    uint2 u = *(const uint2*)p;
    __half2 a = *(__half2*)&u.x;
    __half2 b = *(__half2*)&u.y;
    float2 f0 = __half22float2(a);
    float2 f1 = __half22float2(b);
    return make_float4(f0.x, f0.y, f1.x, f1.y);
}

// dot of 4 halves x 4 halves accumulated into f32 (2x v_dot2_f32_f16)
__device__ __forceinline__ float dot4h(uint2 a, uint2 b, float c) {
    h2v a0 = *(h2v*)&a.x, a1 = *(h2v*)&a.y;
    h2v b0 = *(h2v*)&b.x, b1 = *(h2v*)&b.y;
    return __builtin_amdgcn_fdot2(a0, b0, __builtin_amdgcn_fdot2(a1, b1, c, false), false);
}

// ---- pass A: per-block LDS histogram + local scan + locally-sorted staging ----
__global__ void k_hist(const int* __restrict__ ei, unsigned char* __restrict__ hist8,
                       unsigned short* __restrict__ lrow16,
                       unsigned short* __restrict__ stagedG) {
    __shared__ int lh[NPAIR];                 // 40 KB: counts -> packed lrow
    __shared__ unsigned short sdst[CHUNK];    // 40 KB
    __shared__ unsigned short ssrc[CHUNK];    // 40 KB
    __shared__ int partial[1024];             // 4 KB
    int t = blockIdx.x & 7, b = blockIdx.x >> 3;
    for (int i = threadIdx.x; i < NPAIR; i += 1024) lh[i] = 0;
    __syncthreads();
    const int* srcp = ei + (size_t)t * 2 * E_EDGES + b * CHUNK;
    const int* dstp = srcp + E_EDGES;
    for (int j = threadIdx.x; j < CHUNK; j += 1024) {
        int dst = dstp[j];
        int src = srcp[j];
        sdst[j] = (unsigned short)dst;
        ssrc[j] = (unsigned short)src;
        atomicAdd(&lh[dst >> 1], (dst & 1) ? 65536 : 1);
    }
    __syncthreads();
    size_t bi = (size_t)t * GB + b;
    unsigned char* hp = hist8 + bi * N_NODES;
    for (int i = threadIdx.x; i < NPAIR; i += 1024) {
        int v = lh[i];
        uchar2 pk;
        pk.x = (unsigned char)(v & 0xff);
        pk.y = (unsigned char)((v >> 16) & 0xff);
        *(uchar2*)(hp + 2 * i) = pk;
    }
    __syncthreads();
    const int tpp = 10;   // 1024*10 >= NPAIR
    int i0 = threadIdx.x * tpp;
    int run = 0;
    for (int k = 0; k < tpp; ++k) {
        int i = i0 + k;
        if (i < NPAIR) {
            int v = lh[i];
            run += (v & 0xffff) + (v >> 16);
        }
    }
    partial[threadIdx.x] = run;
    __syncthreads();
    for (int off = 1; off < 1024; off <<= 1) {
        int add = (threadIdx.x >= off) ? partial[threadIdx.x - off] : 0;
        __syncthreads();
        partial[threadIdx.x] += add;
        __syncthreads();
    }
    int run2 = (threadIdx.x > 0) ? partial[threadIdx.x - 1] : 0;
    for (int k = 0; k < tpp; ++k) {
        int i = i0 + k;
        if (i < NPAIR) {
            int v = lh[i];
            int c0 = v & 0xffff, c1 = v >> 16;
            lh[i] = run2 | ((run2 + c0) << 16);   // packed (l0, l1)
            run2 += c0 + c1;
        }
    }
    __syncthreads();
    unsigned short* lp = lrow16 + bi * NPAIR;
    for (int i = threadIdx.x; i < NPAIR; i += 1024)
        lp[i] = (unsigned short)(lh[i] & 0xffff);
    __syncthreads();   // all lrow reads of lh done before atomics mutate lh
    unsigned short* stg = stagedG + bi * CHUNK;
    for (int j = threadIdx.x; j < CHUNK; j += 1024) {
        int dst = sdst[j];
        int old = atomicAdd(&lh[dst >> 1], (dst & 1) ? 65536 : 1);
        int pos = (old >> (16 * (dst & 1))) & 0xffff;
        stg[pos] = ssrc[j];
    }
}

// ---- pass B: per-(t,dst) prefix over blocks -> base (packed) + totals ----
__global__ void k_blkpre(const unsigned char* __restrict__ hist8, int* __restrict__ base,
                         int* __restrict__ cnt, const float* __restrict__ W1,
                         const float* __restrict__ as1, const float* __restrict__ ad1,
                         float* __restrict__ S4) {
    int i = blockIdx.x * blockDim.x + threadIdx.x;  // (t, pair)
    if (i == 0) {
        for (int hd = 0; hd < HEADS; ++hd) {
            float ss = 0.f, sd = 0.f;
            for (int c = 0; c < HDIM; ++c) {
                ss += W1[hd * HDIM + c] * as1[hd * HDIM + c];
                sd += W1[hd * HDIM + c] * ad1[hd * HDIM + c];
            }
            S4[hd] = ss;
            S4[HEADS + hd] = sd;
        }
    }
    if (i >= T_STEPS * NPAIR) return;
    int t = i / NPAIR, pr = i % NPAIR;
    int a0 = 0, a1 = 0;
    for (int b = 0; b < GB; ++b) {
        size_t bi = ((size_t)t * GB + b);
        uchar2 v = *(const uchar2*)(hist8 + bi * N_NODES + 2 * pr);
        base[bi * NPAIR + pr] = a0 | (a1 << 16);
        a0 += v.x;
        a1 += v.y;
    }
    cnt[t * N_NODES + 2 * pr] = a0;
    cnt[t * N_NODES + 2 * pr + 1] = a1;
}

// ---- scan (exclusive) over cnt[TN] -> row[TN+1] ----
__global__ void k_scan_a(const int* __restrict__ cnt, int* __restrict__ bsum) {
    __shared__ int s[256];
    int i = blockIdx.x * 256 + threadIdx.x;
    s[threadIdx.x] = (i < TN) ? cnt[i] : 0;
    __syncthreads();
    for (int off = 128; off > 0; off >>= 1) {
        if (threadIdx.x < off) s[threadIdx.x] += s[threadIdx.x + off];
        __syncthreads();
    }
    if (threadIdx.x == 0) bsum[blockIdx.x] = s[0];
}

__global__ void k_scan_b(const int* __restrict__ bsum, int* __restrict__ bpre) {
    __shared__ int s[256];
    __shared__ int carry;
    if (threadIdx.x == 0) carry = 0;
    __syncthreads();
    for (int base = 0; base < SCAN_BLOCKS; base += 256) {
        int i = base + threadIdx.x;
        int v = (i < SCAN_BLOCKS) ? bsum[i] : 0;
        s[threadIdx.x] = v;
        __syncthreads();
        for (int off = 1; off < 256; off <<= 1) {
            int add = (threadIdx.x >= off) ? s[threadIdx.x - off] : 0;
            __syncthreads();
            s[threadIdx.x] += add;
            __syncthreads();
        }
        if (i < SCAN_BLOCKS) bpre[i] = carry + s[threadIdx.x] - v;  // exclusive
        __syncthreads();
        if (threadIdx.x == 0) carry += s[255];
        __syncthreads();
    }
}

__global__ void k_scan_c(const int* __restrict__ cnt, const int* __restrict__ bpre,
                         int* __restrict__ row) {
    __shared__ int s[256];
    int i = blockIdx.x * 256 + threadIdx.x;
    int v = (i < TN) ? cnt[i] : 0;
    s[threadIdx.x] = v;
    __syncthreads();
    for (int off = 1; off < 256; off <<= 1) {
        int add = (threadIdx.x >= off) ? s[threadIdx.x - off] : 0;
        __syncthreads();
        s[threadIdx.x] += add;
        __syncthreads();
    }
    if (i < TN) row[i] = bpre[blockIdx.x] + s[threadIdx.x] - v;
    if (blockIdx.x == 0 && threadIdx.x == 0) row[TN] = TE;
}

// ---- pass C: per-bin copy from locally-sorted staging into global CSR ----
__global__ void k_scatter(const unsigned char* __restrict__ hist8,
                          const unsigned short* __restrict__ lrow16,
                          const int* __restrict__ row, const int* __restrict__ base,
                          const unsigned short* __restrict__ stagedG,
                          unsigned short* __restrict__ es) {
    int t = blockIdx.x & 7;
    int b = blockIdx.x >> 3;          // 0..31
    size_t bi = (size_t)t * GB + b;
    const unsigned char* h8 = hist8 + bi * N_NODES;
    const unsigned short* lr = lrow16 + bi * NPAIR;
    const int* bs = base + bi * NPAIR;
    const unsigned short* stg = stagedG + bi * CHUNK;
    const int* rw = row + t * N_NODES;
    for (int i = threadIdx.x; i < NPAIR; i += blockDim.x) {
        uchar2 c = *(const uchar2*)(h8 + 2 * i);
        int l0 = lr[i];
        int l1 = l0 + c.x;
        int bp = bs[i];
        int b0 = bp & 0xffff, b1 = (bp >> 16) & 0xffff;
        int2 rr = *(const int2*)(rw + 2 * i);
        for (int k = 0; k < c.x; ++k) es[rr.x + b0 + k] = stg[l0 + k];
        for (int k = 0; k < c.y; ++k) es[rr.y + b1 + k] = stg[l1 + k];
    }
}

// ---- GAT1 reduce: ONE THREAD per (t,dst) bin; ushort4 es loads + unroll-4 ----
__global__ void k_gat1red(const unsigned short* __restrict__ es, const int* __restrict__ row,
                          const float* __restrict__ x, const float* __restrict__ S4,
                          float* __restrict__ inv) {
    int wid = blockIdx.x * 256 + threadIdx.x;  // grid exact: 625*256 == TN
    int t = wid / N_NODES;
    int start = row[wid], end = row[wid + 1];
    float Ss0 = S4[0], Ss1 = S4[1], Sd0 = S4[2], Sd1 = S4[3];
    float xd = x[wid];
    float a0 = xd * Sd0, a1 = xd * Sd1;
    const float* xt = x + (size_t)t * N_NODES;
    // self-loop init
    float w0 = __expf(lrelu02(fmaf(xd, Ss0, a0))), w1 = __expf(lrelu02(fmaf(xd, Ss1, a1)));
    float d0 = w0, n0 = w0 * xd, d1 = w1, n1 = w1 * xd;

#define G1E(xs) { \
    float v0 = __expf(lrelu02(fmaf(xs, Ss0, a0))); \
    float v1 = __expf(lrelu02(fmaf(xs, Ss1, a1))); \
    d0 += v0; n0 = fmaf(v0, xs, n0); \
    d1 += v1; n1 = fmaf(v1, xs, n1); }

    int p = start;
    {
        int nh = (4 - (start & 3)) & 3;
        if (nh > end - start) nh = end - start;
        if (nh > 0) {
            float xa = xt[es[p]];
            float xb = (nh > 1) ? xt[es[p + 1]] : 0.f;
            float xc = (nh > 2) ? xt[es[p + 2]] : 0.f;
            G1E(xa)
            if (nh > 1) G1E(xb)
            if (nh > 2) G1E(xc)
            p += nh;
        }
    }
    for (; p + 3 < end; p += 4) {
        ushort4 e4 = *(const ushort4*)(es + p);
        float xa = xt[e4.x], xb = xt[e4.y], xc = xt[e4.z], xe = xt[e4.w];
        float va0 = __expf(lrelu02(fmaf(xa, Ss0, a0)));
        float va1 = __expf(lrelu02(fmaf(xa, Ss1, a1)));
        float vb0 = __expf(lrelu02(fmaf(xb, Ss0, a0)));
        float vb1 = __expf(lrelu02(fmaf(xb, Ss1, a1)));
        float vc0 = __expf(lrelu02(fmaf(xc, Ss0, a0)));
        float vc1 = __expf(lrelu02(fmaf(xc, Ss1, a1)));
        float ve0 = __expf(lrelu02(fmaf(xe, Ss0, a0)));
        float ve1 = __expf(lrelu02(fmaf(xe, Ss1, a1)));
        d0 += va0 + vb0 + vc0 + ve0;
        d1 += va1 + vb1 + vc1 + ve1;
        n0 = fmaf(va0, xa, fmaf(vb0, xb, fmaf(vc0, xc, fmaf(ve0, xe, n0))));
        n1 = fmaf(va1, xa, fmaf(vb1, xb, fmaf(vc1, xc, fmaf(ve1, xe, n1))));
    }
    {
        int nt = end - p;
        if (nt > 0) {
            float xa = xt[es[p]];
            float xb = (nt > 1) ? xt[es[p + 1]] : 0.f;
            float xc = (nt > 2) ? xt[es[p + 2]] : 0.f;
            G1E(xa)
            if (nt > 1) G1E(xb)
            if (nt > 2) G1E(xc)
        }
    }
#undef G1E
    inv[(size_t)wid * 2 + 0] = n0 / (d0 + 1e-16f);
    inv[(size_t)wid * 2 + 1] = n1 / (d1 + 1e-16f);
}

// ---- GAT1 epilogue + h2 = elu(z1) @ W2 (FP16) + src-logit FP16 ----
__global__ void k_node1(const float* __restrict__ inv, const float* __restrict__ W1,
                        const float* __restrict__ b1, const float* __restrict__ W2,
                        const float* __restrict__ as2w, const float* __restrict__ ad2w,
                        __half* __restrict__ h2h, __half* __restrict__ sh,
                        float* __restrict__ ad2) {
    __shared__ float sW1[HEADS * HDIM];
    __shared__ float sb1[HEADS * HDIM];
    __shared__ float sW2[HEADS * HDIM * (HDIM + 1)];
    __shared__ float sas[HDIM], sad[HDIM];
    __shared__ float z1s[NPB][HEADS * HDIM + 1];

    for (int i = threadIdx.x; i < HEADS * HDIM; i += blockDim.x) {
        sW1[i] = W1[i];
        sb1[i] = b1[i];
    }
    for (int i = threadIdx.x; i < HEADS * HDIM * HDIM; i += blockDim.x) {
        int k = i >> 5, c = i & 31;
        sW2[k * (HDIM + 1) + c] = W2[i];
    }
    for (int i = threadIdx.x; i < HDIM; i += blockDim.x) {
        sas[i] = as2w[i];
        sad[i] = ad2w[i];
    }
    __syncthreads();

    int ln = threadIdx.x >> 5;
    int c = threadIdx.x & 31;
    int tn = blockIdx.x * NPB + ln;
    if (tn >= TN) return;

    float inv0 = inv[(size_t)tn * 2 + 0];
    float inv1 = inv[(size_t)tn * 2 + 1];
    z1s[ln][c] = eluf(inv0 * sW1[c] + sb1[c]);
    z1s[ln][HDIM + c] = eluf(inv1 * sW1[HDIM + c] + sb1[HDIM + c]);
    __syncthreads();

    float acc = 0.f;
#pragma unroll
    for (int k = 0; k < HEADS * HDIM; ++k)
        acc += z1s[ln][k] * sW2[k * (HDIM + 1) + c];

    h2h[(size_t)tn * HDIM + c] = __float2half_rn(acc);
    float s = lane32_sum(acc * sas[c]);
    float d = lane32_sum(acc * sad[c]);
    if (c == 0) {
        sh[tn] = __float2half_rn(s);   // src logit (fp16)
        ad2[tn] = d;
    }
}

// ---- GAT2 reduce: ONE WAVE per block; outputs z2 as FP16 ----
__global__ void k_gat2red(const unsigned short* __restrict__ es, const int* __restrict__ row,
                          const __half* __restrict__ sh, const float* __restrict__ ad2,
                          const __half* __restrict__ h2h, const float* __restrict__ b2,
                          __half* __restrict__ z2h) {
    int b = blockIdx.x;
    int t = b & 7;            // XCD pin
    int chunk = b >> 3;       // 0..2499
    int lane = threadIdx.x;   // block = 64 threads = 1 wave
    int u = lane >> 3;        // node slot 0..7
    int l = lane & 7;         // channel quad: channels 4l..4l+3
    int node = chunk * 8 + u; // exact: 2500*8 == 20000
    int wid = t * N_NODES + node;

    int start = row[wid], end = row[wid + 1];
    float ad = ad2[wid];
    const __half* sht = sh + (size_t)t * N_NODES;
    const __half* h2t = h2h + (size_t)t * N_NODES * HDIM;

    float4 acc = make_float4(0.f, 0.f, 0.f, 0.f);
    float den = 0.f;

#define G2W(sv) __expf(lrelu02(__half2float(sht[sv]) + ad))
#define G2E(sv) { \
    float w = G2W(sv); \
    float4 hv = ldh4(h2t + (size_t)(sv) * HDIM + 4 * l); \
    acc.x = fmaf(w, hv.x, acc.x); \
    acc.y = fmaf(w, hv.y, acc.y); \
    acc.z = fmaf(w, hv.z, acc.z); \
    acc.w = fmaf(w, hv.w, acc.w); \
    den += w; }

    int p = start;
    {
        int nh = (4 - (start & 3)) & 3;
        if (nh > end - start) nh = end - start;
        if (nh > 0) {
            int sh0 = es[p];
            int sh1 = (nh > 1) ? es[p + 1] : 0;
            int sh2 = (nh > 2) ? es[p + 2] : 0;
            G2E(sh0)
            if (nh > 1) G2E(sh1)
            if (nh > 2) G2E(sh2)
            p += nh;
        }
    }
    for (; p + 7 < end; p += 8) {
        ushort4 eA = *(const ushort4*)(es + p);
        ushort4 eB = *(const ushort4*)(es + p + 4);
        int s0 = eA.x, s1 = eA.y, s2 = eA.z, s3 = eA.w;
        int s4 = eB.x, s5 = eB.y, s6 = eB.z, s7 = eB.w;
        float v0 = __half2float(sht[s0]), v1 = __half2float(sht[s1]);
        float v2 = __half2float(sht[s2]), v3 = __half2float(sht[s3]);
        float v4 = __half2float(sht[s4]), v5 = __half2float(sht[s5]);
        float v6 = __half2float(sht[s6]), v7 = __half2float(sht[s7]);
        float4 h0 = ldh4(h2t + (size_t)s0 * HDIM + 4 * l);
        float4 h1 = ldh4(h2t + (size_t)s1 * HDIM + 4 * l);
        float4 h2q = ldh4(h2t + (size_t)s2 * HDIM + 4 * l);
        float4 h3 = ldh4(h2t + (size_t)s3 * HDIM + 4 * l);
        float4 h4 = ldh4(h2t + (size_t)s4 * HDIM + 4 * l);
        float4 h5 = ldh4(h2t + (size_t)s5 * HDIM + 4 * l);
        float4 h6 = ldh4(h2t + (size_t)s6 * HDIM + 4 * l);
        float4 h7 = ldh4(h2t + (size_t)s7 * HDIM + 4 * l);
        float w0 = __expf(lrelu02(v0 + ad));
        float w1 = __expf(lrelu02(v1 + ad));
        float w2 = __expf(lrelu02(v2 + ad));
        float w3 = __expf(lrelu02(v3 + ad));
        float w4 = __expf(lrelu02(v4 + ad));
        float w5 = __expf(lrelu02(v5 + ad));
        float w6 = __expf(lrelu02(v6 + ad));
        float w7 = __expf(lrelu02(v7 + ad));
        acc.x = fmaf(w0, h0.x, fmaf(w1, h1.x, fmaf(w2, h2q.x, fmaf(w3, h3.x, acc.x))));
        acc.x = fmaf(w4, h4.x, fmaf(w5, h5.x, fmaf(w6, h6.x, fmaf(w7, h7.x, acc.x))));
        acc.y = fmaf(w0, h0.y, fmaf(w1, h1.y, fmaf(w2, h2q.y, fmaf(w3, h3.y, acc.y))));
        acc.y = fmaf(w4, h4.y, fmaf(w5, h5.y, fmaf(w6, h6.y, fmaf(w7, h7.y, acc.y))));
        acc.z = fmaf(w0, h0.z, fmaf(w1, h1.z, fmaf(w2, h2q.z, fmaf(w3, h3.z, acc.z))));
        acc.z = fmaf(w4, h4.z, fmaf(w5, h5.z, fmaf(w6, h6.z, fmaf(w7, h7.z, acc.z))));
        acc.w = fmaf(w0, h0.w, fmaf(w1, h1.w, fmaf(w2, h2q.w, fmaf(w3, h3.w, acc.w))));
        acc.w = fmaf(w4, h4.w, fmaf(w5, h5.w, fmaf(w6, h6.w, fmaf(w7, h7.w, acc.w))));
        den += (w0 + w1 + w2 + w3) + (w4 + w5 + w6 + w7);
    }
    if (p + 3 < end) {
        ushort4 eA = *(const ushort4*)(es + p);
        int s0 = eA.x, s1 = eA.y, s2 = eA.z, s3 = eA.w;
        float v0 = __half2float(sht[s0]), v1 = __half2float(sht[s1]);
        float v2 = __half2float(sht[s2]), v3 = __half2float(sht[s3]);
        float4 h0 = ldh4(h2t + (size_t)s0 * HDIM + 4 * l);
        float4 h1 = ldh4(h2t + (size_t)s1 * HDIM + 4 * l);
        float4 h2q = ldh4(h2t + (size_t)s2 * HDIM + 4 * l);
        float4 h3 = ldh4(h2t + (size_t)s3 * HDIM + 4 * l);
        float w0 = __expf(lrelu02(v0 + ad));
        float w1 = __expf(lrelu02(v1 + ad));
        float w2 = __expf(lrelu02(v2 + ad));
        float w3 = __expf(lrelu02(v3 + ad));
        acc.x = fmaf(w0, h0.x, fmaf(w1, h1.x, fmaf(w2, h2q.x, fmaf(w3, h3.x, acc.x))));
        acc.y = fmaf(w0, h0.y, fmaf(w1, h1.y, fmaf(w2, h2q.y, fmaf(w3, h3.y, acc.y))));
        acc.z = fmaf(w0, h0.z, fmaf(w1, h1.z, fmaf(w2, h2q.z, fmaf(w3, h3.z, acc.z))));
        acc.w = fmaf(w0, h0.w, fmaf(w1, h1.w, fmaf(w2, h2q.w, fmaf(w3, h3.w, acc.w))));
        den += w0 + w1 + w2 + w3;
        p += 4;
    }
    {
        int nt = end - p;
        if (nt > 0) {
            int st0 = es[p];
            int st1 = (nt > 1) ? es[p + 1] : 0;
            int st2 = (nt > 2) ? es[p + 2] : 0;
            G2E(st0)
            if (nt > 1) G2E(st1)
            if (nt > 2) G2E(st2)
        }
    }
    // self-loop
    G2E(node)
#undef G2E
#undef G2W

    float invd = 1.f / (den + 1e-16f);
    float4 bb = *(const float4*)(b2 + 4 * l);
    // fp16 output (GRU consumes fp16 via dot2)
    __half o0 = __float2half_rn(eluf(fmaf(acc.x, invd, bb.x)));
    __half o1 = __float2half_rn(eluf(fmaf(acc.y, invd, bb.y)));
    __half o2 = __float2half_rn(eluf(fmaf(acc.z, invd, bb.z)));
    __half o3 = __float2half_rn(eluf(fmaf(acc.w, invd, bb.w)));
    ushort4 pk;
    pk.x = *(unsigned short*)&o0;
    pk.y = *(unsigned short*)&o1;
    pk.z = *(unsigned short*)&o2;
    pk.w = *(unsigned short*)&o3;
    *(ushort4*)(z2h + (size_t)wid * HDIM + 4 * l) = pk;
}

// ---- fused 8-step GRU + output projection, FP16 weights + v_dot2_f32_f16.
// Round-22 lesson: fp32 b128 weight reads were a structural 4-way LDS
// conflict (7.68M/dispatch) and the kernel was LDS-pipe bound (~50 us model).
// fp16 rows (64 B) + row-dependent swizzle key (r ^ (r>>3)) & 7 -> b64 reads,
// residual sharing 2-way (free). Dots via fdot2 halve VALU. h carried fp32
// in registers; LDS h copy fp16 (only used for cross-channel dots).
__global__ void k_gru_all(const __half* __restrict__ z2h, const float* __restrict__ Wih,
                          const float* __restrict__ Whh, const float* __restrict__ bih,
                          const float* __restrict__ bhh, const float* __restrict__ Wout,
                          const float* __restrict__ bout, float* __restrict__ out) {
    __shared__ __half sWih[3 * HDIM * 32];  // 6 KB, swizzled
    __shared__ __half sWhh[3 * HDIM * 32];
    __shared__ float sbih[3 * HDIM], sbhh[3 * HDIM], sWout[HDIM];
    __shared__ __half hls[GNB * 32];        // 1 KB
    __shared__ __half zls[GNB * 32];

    for (int i = threadIdx.x; i < 3 * HDIM * HDIM; i += 256) {
        int r = i >> 5, cc = i & 31;
        int key = (r ^ (r >> 3)) & 7;
        int pos = r * 32 + ((((cc >> 2) ^ key) << 2) | (cc & 3));
        sWih[pos] = __float2half_rn(Wih[i]);
        sWhh[pos] = __float2half_rn(Whh[i]);
    }
    for (int i = threadIdx.x; i < 3 * HDIM; i += 256) {
        sbih[i] = bih[i];
        sbhh[i] = bhh[i];
    }
    for (int i = threadIdx.x; i < HDIM; i += 256) sWout[i] = Wout[i];
    for (int i = threadIdx.x; i < GNB * 32; i += 256) hls[i] = __float2half_rn(0.f);
    __syncthreads();

    const int c = threadIdx.x & 31;
    const int nb = (threadIdx.x >> 5) * GNT;
    const int gbase = blockIdx.x * GNB;
    // swizzle keys for this thread's three gate rows (r, z, n)
    const int rR = c, rZ = HDIM + c, rN = 2 * HDIM + c;
    const int kR = (rR ^ (rR >> 3)) & 7;
    const int kZ = (rZ ^ (rZ >> 3)) & 7;
    const int kN = (rN ^ (rN >> 3)) & 7;

    const float br = sbih[c], bz = sbih[HDIM + c], bn = sbih[2 * HDIM + c];
    const float cr = sbhh[c], cz = sbhh[HDIM + c], cn = sbhh[2 * HDIM + c];

    float air0, aiz0, ain0, ahr0, ahz0, ahn0, hr0;
    float air1, aiz1, ain1, ahr1, ahz1, ahn1, hr1;
    hr0 = hr1 = 0.f;

    for (int t = 0; t < T_STEPS; ++t) {
        // stage z2h tile (16 nodes x 32 halves = 1 KB = 128 uint2)
        const uint2* zsrc = (const uint2*)(z2h + ((size_t)t * N_NODES + gbase) * HDIM);
        if (threadIdx.x < GNB * 8)
            *(uint2*)&zls[threadIdx.x * 4] = zsrc[threadIdx.x];
        __syncthreads();

        air0 = air1 = br;
        aiz0 = aiz1 = bz;
        ain0 = ain1 = bn;
        ahr0 = ahr1 = cr;
        ahz0 = ahz1 = cz;
        ahn0 = ahn1 = cn;
#pragma unroll 2
        for (int q = 0; q < 8; ++q) {
            int kq = q << 2;
            uint2 wri = *(const uint2*)&sWih[rR * 32 + ((q ^ kR) << 2)];
            uint2 wzi = *(const uint2*)&sWih[rZ * 32 + ((q ^ kZ) << 2)];
            uint2 wni = *(const uint2*)&sWih[rN * 32 + ((q ^ kN) << 2)];
            uint2 wrh = *(const uint2*)&sWhh[rR * 32 + ((q ^ kR) << 2)];
            uint2 wzh = *(const uint2*)&sWhh[rZ * 32 + ((q ^ kZ) << 2)];
            uint2 wnh = *(const uint2*)&sWhh[rN * 32 + ((q ^ kN) << 2)];
            uint2 zv0 = *(const uint2*)&zls[(nb + 0) * 32 + kq];
            uint2 hv0 = *(const uint2*)&hls[(nb + 0) * 32 + kq];
            uint2 zv1 = *(const uint2*)&zls[(nb + 1) * 32 + kq];
            uint2 hv1 = *(const uint2*)&hls[(nb + 1) * 32 + kq];
            air0 = dot4h(wri, zv0, air0);
            aiz0 = dot4h(wzi, zv0, aiz0);
            ain0 = dot4h(wni, zv0, ain0);
            ahr0 = dot4h(wrh, hv0, ahr0);
            ahz0 = dot4h(wzh, hv0, ahz0);
            ahn0 = dot4h(wnh, hv0, ahn0);
            air1 = dot4h(wri, zv1, air1);
            aiz1 = dot4h(wzi, zv1, aiz1);
            ain1 = dot4h(wni, zv1, ain1);
            ahr1 = dot4h(wrh, hv1, ahr1);
            ahz1 = dot4h(wzh, hv1, ahz1);
            ahn1 = dot4h(wnh, hv1, ahn1);
        }
        {
            float r = fsig(air0 + ahr0);
            float z = fsig(aiz0 + ahz0);
            float g = ftanh(ain0 + r * ahn0);
            hr0 = (1.f - z) * g + z * hr0;
            hls[(nb + 0) * 32 + c] = __float2half_rn(hr0);
        }
        {
            float r = fsig(air1 + ahr1);
            float z = fsig(aiz1 + ahz1);
            float g = ftanh(ain1 + r * ahn1);
            hr1 = (1.f - z) * g + z * hr1;
            hls[(nb + 1) * 32 + c] = __float2half_rn(hr1);
        }
        __syncthreads();
    }

    float wo = sWout[c];
    float s0 = lane32_sum(hr0 * wo);
    float s1 = lane32_sum(hr1 * wo);
    if (c == 0) {
        float bo = bout[0];
        out[gbase + nb + 0] = s0 + bo;
        out[gbase + nb + 1] = s1 + bo;
    }
}

extern "C" void kernel_launch(void* const* d_in, const int* in_sizes, int n_in,
                              void* d_out, int out_size, void* d_ws, size_t ws_size,
                              hipStream_t stream) {
    const float* x      = (const float*)d_in[0];   // T*N
    const int* eidx     = (const int*)d_in[1];     // T*2*E
    const float* W1     = (const float*)d_in[2];
    const float* a_src1 = (const float*)d_in[3];
    const float* a_dst1 = (const float*)d_in[4];
    const float* b1     = (const float*)d_in[5];
    const float* W2     = (const float*)d_in[6];
    const float* a_src2 = (const float*)d_in[7];
    const float* a_dst2 = (const float*)d_in[8];
    const float* b2     = (const float*)d_in[9];
    const float* W_ih   = (const float*)d_in[10];
    const float* W_hh   = (const float*)d_in[11];
    const float* b_ih   = (const float*)d_in[12];
    const float* b_hh   = (const float*)d_in[13];
    const float* W_out  = (const float*)d_in[14];
    const float* b_out  = (const float*)d_in[15];
    float* out = (float*)d_out;

    char* base_ws = (char*)d_ws;
    size_t off = 0;
    auto alloc = [&](size_t bytes) {
        char* p = base_ws + off;
        off = (off + bytes + 15) & ~(size_t)15;
        return p;
    };
    int* cnt             = (int*)alloc((size_t)TN * 4);
    int* row             = (int*)alloc((size_t)(TN + 1) * 4);
    int* bsum            = (int*)alloc((size_t)SCAN_BLOCKS * 4);
    int* bpre            = (int*)alloc((size_t)SCAN_BLOCKS * 4);
    float* inv           = (float*)alloc((size_t)TN * 2 * 4);
    __half* h2h          = (__half*)alloc((size_t)TN * HDIM * 2);   // 10.24 MB
    __half* sh           = (__half*)alloc((size_t)TN * 2);          // 320 KB
    float* ad2           = (float*)alloc((size_t)TN * 4);
    __half* z2h          = (__half*)alloc((size_t)TN * HDIM * 2);   // 10.24 MB
    float* S4            = (float*)alloc(16);
    unsigned short* es   = (unsigned short*)alloc((size_t)TE * 2);  // 10.24 MB
    int* bbase           = (int*)alloc((size_t)T_STEPS * GB * NPAIR * 4);   // 10.24 MB
    unsigned short* stagedG = (unsigned short*)alloc((size_t)TE * 2);       // 10.24 MB
    // Aliases (stream-order safe):
    //  h2h region = hist8 (5.12 MB u8) + lrow16 (5.12 MB u16): written by
    //  hist, read by blkpre/scatter; h2h written later by node1.
    unsigned char* hist8   = (unsigned char*)h2h;
    unsigned short* lrow16 = (unsigned short*)((char*)h2h + (size_t)T_STEPS * GB * N_NODES);

    const int B = 256;
    k_hist<<<8 * GB, 1024, 0, stream>>>(eidx, hist8, lrow16, stagedG);
    k_blkpre<<<(T_STEPS * NPAIR + B - 1) / B, B, 0, stream>>>(hist8, bbase, cnt,
                                                              W1, a_src1, a_dst1, S4);
    k_scan_a<<<SCAN_BLOCKS, B, 0, stream>>>(cnt, bsum);
    k_scan_b<<<1, B, 0, stream>>>(bsum, bpre);
    k_scan_c<<<SCAN_BLOCKS, B, 0, stream>>>(cnt, bpre, row);
    k_scatter<<<8 * GB, 512, 0, stream>>>(hist8, lrow16, row, bbase, stagedG, es);

    k_gat1red<<<TN / 256, B, 0, stream>>>(es, row, x, S4, inv);
    k_node1<<<TN / NPB, B, 0, stream>>>(inv, W1, b1, W2, a_src2, a_dst2, h2h, sh, ad2);
    k_gat2red<<<TN / 8, 64, 0, stream>>>(es, row, sh, ad2, h2h, b2, z2h);

    k_gru_all<<<N_NODES / GNB, B, 0, stream>>>(z2h, W_ih, W_hh, b_ih, b_hh, W_out, b_out, out);
}

// Round 24
// 272.328 us; speedup vs baseline: 1.1438x; 1.0512x over previous
//
#include <hip/hip_runtime.h>
#include <hip/hip_fp16.h>
#include <math.h>

#define N_NODES 20000
#define T_STEPS 8
#define E_EDGES 640000
#define TN (T_STEPS * N_NODES)   // 160000
#define TE (T_STEPS * E_EDGES)   // 5120000
#define HDIM 32
#define HEADS 2
#define NPB 8                    // nodes per block for lane-parallel node kernels
#define SCAN_BLOCKS 625          // TN / 256 exactly
#define GB 32                    // histogram blocks per timestep
#define CHUNK (E_EDGES / GB)     // 20000 edges per histogram block
#define NPAIR (N_NODES / 2)      // packed bins per timestep
#define GNT 2                    // GRU nodes per thread-group
#define GNB (8 * GNT)            // GRU nodes per block = 16 (1250 blocks exactly)

typedef _Float16 h2v __attribute__((ext_vector_type(2)));

__device__ __forceinline__ float lrelu02(float v) { return fmaxf(v, 0.2f * v); }
__device__ __forceinline__ float eluf(float v) { return v > 0.f ? v : expm1f(v); }
__device__ __forceinline__ float fsig(float v) {
    return __fdividef(1.f, 1.f + __expf(-v));
}
__device__ __forceinline__ float ftanh(float v) {
    return 1.f - __fdividef(2.f, __expf(2.f * v) + 1.f);
}

__device__ __forceinline__ float lane32_sum(float v) {
    v += __shfl_xor(v, 16);
    v += __shfl_xor(v, 8);
    v += __shfl_xor(v, 4);
    v += __shfl_xor(v, 2);
    v += __shfl_xor(v, 1);
    return v;
}

// load 4 fp16 channels (8 B, one dword2) -> float4
__device__ __forceinline__ float4 ldh4(const __half* p) {
    uint2 u = *(const uint2*)p;
    __half2 a = *(__half2*)&u.x;
    __half2 b = *(__half2*)&u.y;
    float2 f0 = __half22float2(a);
    float2 f1 = __half22float2(b);
    return make_float4(f0.x, f0.y, f1.x, f1.y);
}

// dot of 4 halves x 4 halves accumulated into f32 (2x v_dot2_f32_f16)
__device__ __forceinline__ float dot4h(uint2 a, uint2 b, float c) {
    h2v a0 = *(h2v*)&a.x, a1 = *(h2v*)&a.y;
    h2v b0 = *(h2v*)&b.x, b1 = *(h2v*)&b.y;
    return __builtin_amdgcn_fdot2(a0, b0, __builtin_amdgcn_fdot2(a1, b1, c, false), false);
}

// ---- pass A: per-block LDS histogram + local scan + locally-sorted staging ----
__global__ void k_hist(const int* __restrict__ ei, unsigned char* __restrict__ hist8,
                       unsigned short* __restrict__ lrow16,
                       unsigned short* __restrict__ stagedG) {
    __shared__ int lh[NPAIR];                 // 40 KB: counts -> packed lrow
    __shared__ unsigned short sdst[CHUNK];    // 40 KB
    __shared__ unsigned short ssrc[CHUNK];    // 40 KB
    __shared__ int partial[1024];             // 4 KB
    int t = blockIdx.x & 7, b = blockIdx.x >> 3;
    for (int i = threadIdx.x; i < NPAIR; i += 1024) lh[i] = 0;
    __syncthreads();
    const int* srcp = ei + (size_t)t * 2 * E_EDGES + b * CHUNK;
    const int* dstp = srcp + E_EDGES;
    for (int j = threadIdx.x; j < CHUNK; j += 1024) {
        int dst = dstp[j];
        int src = srcp[j];
        sdst[j] = (unsigned short)dst;
        ssrc[j] = (unsigned short)src;
        atomicAdd(&lh[dst >> 1], (dst & 1) ? 65536 : 1);
    }
    __syncthreads();
    size_t bi = (size_t)t * GB + b;
    unsigned char* hp = hist8 + bi * N_NODES;
    for (int i = threadIdx.x; i < NPAIR; i += 1024) {
        int v = lh[i];
        uchar2 pk;
        pk.x = (unsigned char)(v & 0xff);
        pk.y = (unsigned char)((v >> 16) & 0xff);
        *(uchar2*)(hp + 2 * i) = pk;
    }
    __syncthreads();
    const int tpp = 10;   // 1024*10 >= NPAIR
    int i0 = threadIdx.x * tpp;
    int run = 0;
    for (int k = 0; k < tpp; ++k) {
        int i = i0 + k;
        if (i < NPAIR) {
            int v = lh[i];
            run += (v & 0xffff) + (v >> 16);
        }
    }
    partial[threadIdx.x] = run;
    __syncthreads();
    for (int off = 1; off < 1024; off <<= 1) {
        int add = (threadIdx.x >= off) ? partial[threadIdx.x - off] : 0;
        __syncthreads();
        partial[threadIdx.x] += add;
        __syncthreads();
    }
    int run2 = (threadIdx.x > 0) ? partial[threadIdx.x - 1] : 0;
    for (int k = 0; k < tpp; ++k) {
        int i = i0 + k;
        if (i < NPAIR) {
            int v = lh[i];
            int c0 = v & 0xffff, c1 = v >> 16;
            lh[i] = run2 | ((run2 + c0) << 16);   // packed (l0, l1)
            run2 += c0 + c1;
        }
    }
    __syncthreads();
    unsigned short* lp = lrow16 + bi * NPAIR;
    for (int i = threadIdx.x; i < NPAIR; i += 1024)
        lp[i] = (unsigned short)(lh[i] & 0xffff);
    __syncthreads();   // all lrow reads of lh done before atomics mutate lh
    unsigned short* stg = stagedG + bi * CHUNK;
    for (int j = threadIdx.x; j < CHUNK; j += 1024) {
        int dst = sdst[j];
        int old = atomicAdd(&lh[dst >> 1], (dst & 1) ? 65536 : 1);
        int pos = (old >> (16 * (dst & 1))) & 0xffff;
        stg[pos] = ssrc[j];
    }
}

// ---- pass B: per-(t,dst) prefix over blocks -> base (packed) + totals ----
__global__ void k_blkpre(const unsigned char* __restrict__ hist8, int* __restrict__ base,
                         int* __restrict__ cnt, const float* __restrict__ W1,
                         const float* __restrict__ as1, const float* __restrict__ ad1,
                         float* __restrict__ S4) {
    int i = blockIdx.x * blockDim.x + threadIdx.x;  // (t, pair)
    if (i == 0) {
        for (int hd = 0; hd < HEADS; ++hd) {
            float ss = 0.f, sd = 0.f;
            for (int c = 0; c < HDIM; ++c) {
                ss += W1[hd * HDIM + c] * as1[hd * HDIM + c];
                sd += W1[hd * HDIM + c] * ad1[hd * HDIM + c];
            }
            S4[hd] = ss;
            S4[HEADS + hd] = sd;
        }
    }
    if (i >= T_STEPS * NPAIR) return;
    int t = i / NPAIR, pr = i % NPAIR;
    int a0 = 0, a1 = 0;
    for (int b = 0; b < GB; ++b) {
        size_t bi = ((size_t)t * GB + b);
        uchar2 v = *(const uchar2*)(hist8 + bi * N_NODES + 2 * pr);
        base[bi * NPAIR + pr] = a0 | (a1 << 16);
        a0 += v.x;
        a1 += v.y;
    }
    cnt[t * N_NODES + 2 * pr] = a0;
    cnt[t * N_NODES + 2 * pr + 1] = a1;
}

// ---- scan (exclusive) over cnt[TN] -> row[TN+1] ----
__global__ void k_scan_a(const int* __restrict__ cnt, int* __restrict__ bsum) {
    __shared__ int s[256];
    int i = blockIdx.x * 256 + threadIdx.x;
    s[threadIdx.x] = (i < TN) ? cnt[i] : 0;
    __syncthreads();
    for (int off = 128; off > 0; off >>= 1) {
        if (threadIdx.x < off) s[threadIdx.x] += s[threadIdx.x + off];
        __syncthreads();
    }
    if (threadIdx.x == 0) bsum[blockIdx.x] = s[0];
}

__global__ void k_scan_b(const int* __restrict__ bsum, int* __restrict__ bpre) {
    __shared__ int s[256];
    __shared__ int carry;
    if (threadIdx.x == 0) carry = 0;
    __syncthreads();
    for (int base = 0; base < SCAN_BLOCKS; base += 256) {
        int i = base + threadIdx.x;
        int v = (i < SCAN_BLOCKS) ? bsum[i] : 0;
        s[threadIdx.x] = v;
        __syncthreads();
        for (int off = 1; off < 256; off <<= 1) {
            int add = (threadIdx.x >= off) ? s[threadIdx.x - off] : 0;
            __syncthreads();
            s[threadIdx.x] += add;
            __syncthreads();
        }
        if (i < SCAN_BLOCKS) bpre[i] = carry + s[threadIdx.x] - v;  // exclusive
        __syncthreads();
        if (threadIdx.x == 0) carry += s[255];
        __syncthreads();
    }
}

__global__ void k_scan_c(const int* __restrict__ cnt, const int* __restrict__ bpre,
                         int* __restrict__ row) {
    __shared__ int s[256];
    int i = blockIdx.x * 256 + threadIdx.x;
    int v = (i < TN) ? cnt[i] : 0;
    s[threadIdx.x] = v;
    __syncthreads();
    for (int off = 1; off < 256; off <<= 1) {
        int add = (threadIdx.x >= off) ? s[threadIdx.x - off] : 0;
        __syncthreads();
        s[threadIdx.x] += add;
        __syncthreads();
    }
    if (i < TN) row[i] = bpre[blockIdx.x] + s[threadIdx.x] - v;
    if (blockIdx.x == 0 && threadIdx.x == 0) row[TN] = TE;
}

// ---- pass C: per-bin copy from locally-sorted staging into global CSR ----
__global__ void k_scatter(const unsigned char* __restrict__ hist8,
                          const unsigned short* __restrict__ lrow16,
                          const int* __restrict__ row, const int* __restrict__ base,
                          const unsigned short* __restrict__ stagedG,
                          unsigned short* __restrict__ es) {
    int t = blockIdx.x & 7;
    int b = blockIdx.x >> 3;          // 0..31
    size_t bi = (size_t)t * GB + b;
    const unsigned char* h8 = hist8 + bi * N_NODES;
    const unsigned short* lr = lrow16 + bi * NPAIR;
    const int* bs = base + bi * NPAIR;
    const unsigned short* stg = stagedG + bi * CHUNK;
    const int* rw = row + t * N_NODES;
    for (int i = threadIdx.x; i < NPAIR; i += blockDim.x) {
        uchar2 c = *(const uchar2*)(h8 + 2 * i);
        int l0 = lr[i];
        int l1 = l0 + c.x;
        int bp = bs[i];
        int b0 = bp & 0xffff, b1 = (bp >> 16) & 0xffff;
        int2 rr = *(const int2*)(rw + 2 * i);
        for (int k = 0; k < c.x; ++k) es[rr.x + b0 + k] = stg[l0 + k];
        for (int k = 0; k < c.y; ++k) es[rr.y + b1 + k] = stg[l1 + k];
    }
}

// ---- GAT1 reduce: ONE THREAD per (t,dst) bin; ushort4 es loads + unroll-4 ----
__global__ void k_gat1red(const unsigned short* __restrict__ es, const int* __restrict__ row,
                          const float* __restrict__ x, const float* __restrict__ S4,
                          float* __restrict__ inv) {
    int wid = blockIdx.x * 256 + threadIdx.x;  // grid exact: 625*256 == TN
    int t = wid / N_NODES;
    int start = row[wid], end = row[wid + 1];
    float Ss0 = S4[0], Ss1 = S4[1], Sd0 = S4[2], Sd1 = S4[3];
    float xd = x[wid];
    float a0 = xd * Sd0, a1 = xd * Sd1;
    const float* xt = x + (size_t)t * N_NODES;
    // self-loop init
    float w0 = __expf(lrelu02(fmaf(xd, Ss0, a0))), w1 = __expf(lrelu02(fmaf(xd, Ss1, a1)));
    float d0 = w0, n0 = w0 * xd, d1 = w1, n1 = w1 * xd;

#define G1E(xs) { \
    float v0 = __expf(lrelu02(fmaf(xs, Ss0, a0))); \
    float v1 = __expf(lrelu02(fmaf(xs, Ss1, a1))); \
    d0 += v0; n0 = fmaf(v0, xs, n0); \
    d1 += v1; n1 = fmaf(v1, xs, n1); }

    int p = start;
    {
        int nh = (4 - (start & 3)) & 3;
        if (nh > end - start) nh = end - start;
        if (nh > 0) {
            float xa = xt[es[p]];
            float xb = (nh > 1) ? xt[es[p + 1]] : 0.f;
            float xc = (nh > 2) ? xt[es[p + 2]] : 0.f;
            G1E(xa)
            if (nh > 1) G1E(xb)
            if (nh > 2) G1E(xc)
            p += nh;
        }
    }
    for (; p + 3 < end; p += 4) {
        ushort4 e4 = *(const ushort4*)(es + p);
        float xa = xt[e4.x], xb = xt[e4.y], xc = xt[e4.z], xe = xt[e4.w];
        float va0 = __expf(lrelu02(fmaf(xa, Ss0, a0)));
        float va1 = __expf(lrelu02(fmaf(xa, Ss1, a1)));
        float vb0 = __expf(lrelu02(fmaf(xb, Ss0, a0)));
        float vb1 = __expf(lrelu02(fmaf(xb, Ss1, a1)));
        float vc0 = __expf(lrelu02(fmaf(xc, Ss0, a0)));
        float vc1 = __expf(lrelu02(fmaf(xc, Ss1, a1)));
        float ve0 = __expf(lrelu02(fmaf(xe, Ss0, a0)));
        float ve1 = __expf(lrelu02(fmaf(xe, Ss1, a1)));
        d0 += va0 + vb0 + vc0 + ve0;
        d1 += va1 + vb1 + vc1 + ve1;
        n0 = fmaf(va0, xa, fmaf(vb0, xb, fmaf(vc0, xc, fmaf(ve0, xe, n0))));
        n1 = fmaf(va1, xa, fmaf(vb1, xb, fmaf(vc1, xc, fmaf(ve1, xe, n1))));
    }
    {
        int nt = end - p;
        if (nt > 0) {
            float xa = xt[es[p]];
            float xb = (nt > 1) ? xt[es[p + 1]] : 0.f;
            float xc = (nt > 2) ? xt[es[p + 2]] : 0.f;
            G1E(xa)
            if (nt > 1) G1E(xb)
            if (nt > 2) G1E(xc)
        }
    }
#undef G1E
    inv[(size_t)wid * 2 + 0] = n0 / (d0 + 1e-16f);
    inv[(size_t)wid * 2 + 1] = n1 / (d1 + 1e-16f);
}

// ---- GAT1 epilogue + h2 = elu(z1) @ W2, FP16 dot2 matvec.
// Round-23 lesson: fp32 scalar LDS matvec was LDS-issue bound (128 b32
// reads/thread). W2 stored TRANSPOSED fp16 (sW2T[c][64], 4 KB) with chunk
// XOR swizzle j^(c&15) -> b64 reads, 2 lanes/bank (free). z1 fp16 broadcast.
__global__ void k_node1(const float* __restrict__ inv, const float* __restrict__ W1,
                        const float* __restrict__ b1, const float* __restrict__ W2,
                        const float* __restrict__ as2w, const float* __restrict__ ad2w,
                        __half* __restrict__ h2h, __half* __restrict__ sh,
                        float* __restrict__ ad2) {
    __shared__ float sW1[HEADS * HDIM];
    __shared__ float sb1[HEADS * HDIM];
    __shared__ __half sW2T[HDIM * 64];        // [c][k], swizzled chunks
    __shared__ float sas[HDIM], sad[HDIM];
    __shared__ __half z1h[NPB][HEADS * HDIM]; // [8][64] fp16

    for (int i = threadIdx.x; i < HEADS * HDIM; i += blockDim.x) {
        sW1[i] = W1[i];
        sb1[i] = b1[i];
    }
    for (int i = threadIdx.x; i < HEADS * HDIM * HDIM; i += blockDim.x) {
        int k = i >> 5, c = i & 31;
        int j = k >> 2;                       // true chunk
        int js = j ^ (c & 15);                // stored chunk slot
        sW2T[c * 64 + (js << 2) + (k & 3)] = __float2half_rn(W2[i]);
    }
    for (int i = threadIdx.x; i < HDIM; i += blockDim.x) {
        sas[i] = as2w[i];
        sad[i] = ad2w[i];
    }
    __syncthreads();

    int ln = threadIdx.x >> 5;
    int c = threadIdx.x & 31;
    int tn = blockIdx.x * NPB + ln;
    if (tn >= TN) return;

    float inv0 = inv[(size_t)tn * 2 + 0];
    float inv1 = inv[(size_t)tn * 2 + 1];
    z1h[ln][c] = __float2half_rn(eluf(inv0 * sW1[c] + sb1[c]));
    z1h[ln][HDIM + c] = __float2half_rn(eluf(inv1 * sW1[HDIM + c] + sb1[HDIM + c]));
    __syncthreads();

    float acc = 0.f;
    const int key = c & 15;
#pragma unroll
    for (int j = 0; j < 16; ++j) {
        uint2 w = *(const uint2*)&sW2T[c * 64 + ((j ^ key) << 2)];
        uint2 z = *(const uint2*)&z1h[ln][j << 2];
        acc = dot4h(w, z, acc);
    }

    h2h[(size_t)tn * HDIM + c] = __float2half_rn(acc);
    float s = lane32_sum(acc * sas[c]);
    float d = lane32_sum(acc * sad[c]);
    if (c == 0) {
        sh[tn] = __float2half_rn(s);   // src logit (fp16)
        ad2[tn] = d;
    }
}

// ---- GAT2 reduce: ONE WAVE per block; outputs z2 as FP16 ----
__global__ void k_gat2red(const unsigned short* __restrict__ es, const int* __restrict__ row,
                          const __half* __restrict__ sh, const float* __restrict__ ad2,
                          const __half* __restrict__ h2h, const float* __restrict__ b2,
                          __half* __restrict__ z2h) {
    int b = blockIdx.x;
    int t = b & 7;            // XCD pin
    int chunk = b >> 3;       // 0..2499
    int lane = threadIdx.x;   // block = 64 threads = 1 wave
    int u = lane >> 3;        // node slot 0..7
    int l = lane & 7;         // channel quad: channels 4l..4l+3
    int node = chunk * 8 + u; // exact: 2500*8 == 20000
    int wid = t * N_NODES + node;

    int start = row[wid], end = row[wid + 1];
    float ad = ad2[wid];
    const __half* sht = sh + (size_t)t * N_NODES;
    const __half* h2t = h2h + (size_t)t * N_NODES * HDIM;

    float4 acc = make_float4(0.f, 0.f, 0.f, 0.f);
    float den = 0.f;

#define G2W(sv) __expf(lrelu02(__half2float(sht[sv]) + ad))
#define G2E(sv) { \
    float w = G2W(sv); \
    float4 hv = ldh4(h2t + (size_t)(sv) * HDIM + 4 * l); \
    acc.x = fmaf(w, hv.x, acc.x); \
    acc.y = fmaf(w, hv.y, acc.y); \
    acc.z = fmaf(w, hv.z, acc.z); \
    acc.w = fmaf(w, hv.w, acc.w); \
    den += w; }

    int p = start;
    {
        int nh = (4 - (start & 3)) & 3;
        if (nh > end - start) nh = end - start;
        if (nh > 0) {
            int sh0 = es[p];
            int sh1 = (nh > 1) ? es[p + 1] : 0;
            int sh2 = (nh > 2) ? es[p + 2] : 0;
            G2E(sh0)
            if (nh > 1) G2E(sh1)
            if (nh > 2) G2E(sh2)
            p += nh;
        }
    }
    for (; p + 7 < end; p += 8) {
        ushort4 eA = *(const ushort4*)(es + p);
        ushort4 eB = *(const ushort4*)(es + p + 4);
        int s0 = eA.x, s1 = eA.y, s2 = eA.z, s3 = eA.w;
        int s4 = eB.x, s5 = eB.y, s6 = eB.z, s7 = eB.w;
        float v0 = __half2float(sht[s0]), v1 = __half2float(sht[s1]);
        float v2 = __half2float(sht[s2]), v3 = __half2float(sht[s3]);
        float v4 = __half2float(sht[s4]), v5 = __half2float(sht[s5]);
        float v6 = __half2float(sht[s6]), v7 = __half2float(sht[s7]);
        float4 h0 = ldh4(h2t + (size_t)s0 * HDIM + 4 * l);
        float4 h1 = ldh4(h2t + (size_t)s1 * HDIM + 4 * l);
        float4 h2q = ldh4(h2t + (size_t)s2 * HDIM + 4 * l);
        float4 h3 = ldh4(h2t + (size_t)s3 * HDIM + 4 * l);
        float4 h4 = ldh4(h2t + (size_t)s4 * HDIM + 4 * l);
        float4 h5 = ldh4(h2t + (size_t)s5 * HDIM + 4 * l);
        float4 h6 = ldh4(h2t + (size_t)s6 * HDIM + 4 * l);
        float4 h7 = ldh4(h2t + (size_t)s7 * HDIM + 4 * l);
        float w0 = __expf(lrelu02(v0 + ad));
        float w1 = __expf(lrelu02(v1 + ad));
        float w2 = __expf(lrelu02(v2 + ad));
        float w3 = __expf(lrelu02(v3 + ad));
        float w4 = __expf(lrelu02(v4 + ad));
        float w5 = __expf(lrelu02(v5 + ad));
        float w6 = __expf(lrelu02(v6 + ad));
        float w7 = __expf(lrelu02(v7 + ad));
        acc.x = fmaf(w0, h0.x, fmaf(w1, h1.x, fmaf(w2, h2q.x, fmaf(w3, h3.x, acc.x))));
        acc.x = fmaf(w4, h4.x, fmaf(w5, h5.x, fmaf(w6, h6.x, fmaf(w7, h7.x, acc.x))));
        acc.y = fmaf(w0, h0.y, fmaf(w1, h1.y, fmaf(w2, h2q.y, fmaf(w3, h3.y, acc.y))));
        acc.y = fmaf(w4, h4.y, fmaf(w5, h5.y, fmaf(w6, h6.y, fmaf(w7, h7.y, acc.y))));
        acc.z = fmaf(w0, h0.z, fmaf(w1, h1.z, fmaf(w2, h2q.z, fmaf(w3, h3.z, acc.z))));
        acc.z = fmaf(w4, h4.z, fmaf(w5, h5.z, fmaf(w6, h6.z, fmaf(w7, h7.z, acc.z))));
        acc.w = fmaf(w0, h0.w, fmaf(w1, h1.w, fmaf(w2, h2q.w, fmaf(w3, h3.w, acc.w))));
        acc.w = fmaf(w4, h4.w, fmaf(w5, h5.w, fmaf(w6, h6.w, fmaf(w7, h7.w, acc.w))));
        den += (w0 + w1 + w2 + w3) + (w4 + w5 + w6 + w7);
    }
    if (p + 3 < end) {
        ushort4 eA = *(const ushort4*)(es + p);
        int s0 = eA.x, s1 = eA.y, s2 = eA.z, s3 = eA.w;
        float v0 = __half2float(sht[s0]), v1 = __half2float(sht[s1]);
        float v2 = __half2float(sht[s2]), v3 = __half2float(sht[s3]);
        float4 h0 = ldh4(h2t + (size_t)s0 * HDIM + 4 * l);
        float4 h1 = ldh4(h2t + (size_t)s1 * HDIM + 4 * l);
        float4 h2q = ldh4(h2t + (size_t)s2 * HDIM + 4 * l);
        float4 h3 = ldh4(h2t + (size_t)s3 * HDIM + 4 * l);
        float w0 = __expf(lrelu02(v0 + ad));
        float w1 = __expf(lrelu02(v1 + ad));
        float w2 = __expf(lrelu02(v2 + ad));
        float w3 = __expf(lrelu02(v3 + ad));
        acc.x = fmaf(w0, h0.x, fmaf(w1, h1.x, fmaf(w2, h2q.x, fmaf(w3, h3.x, acc.x))));
        acc.y = fmaf(w0, h0.y, fmaf(w1, h1.y, fmaf(w2, h2q.y, fmaf(w3, h3.y, acc.y))));
        acc.z = fmaf(w0, h0.z, fmaf(w1, h1.z, fmaf(w2, h2q.z, fmaf(w3, h3.z, acc.z))));
        acc.w = fmaf(w0, h0.w, fmaf(w1, h1.w, fmaf(w2, h2q.w, fmaf(w3, h3.w, acc.w))));
        den += w0 + w1 + w2 + w3;
        p += 4;
    }
    {
        int nt = end - p;
        if (nt > 0) {
            int st0 = es[p];
            int st1 = (nt > 1) ? es[p + 1] : 0;
            int st2 = (nt > 2) ? es[p + 2] : 0;
            G2E(st0)
            if (nt > 1) G2E(st1)
            if (nt > 2) G2E(st2)
        }
    }
    // self-loop
    G2E(node)
#undef G2E
#undef G2W

    float invd = 1.f / (den + 1e-16f);
    float4 bb = *(const float4*)(b2 + 4 * l);
    __half o0 = __float2half_rn(eluf(fmaf(acc.x, invd, bb.x)));
    __half o1 = __float2half_rn(eluf(fmaf(acc.y, invd, bb.y)));
    __half o2 = __float2half_rn(eluf(fmaf(acc.z, invd, bb.z)));
    __half o3 = __float2half_rn(eluf(fmaf(acc.w, invd, bb.w)));
    ushort4 pk;
    pk.x = *(unsigned short*)&o0;
    pk.y = *(unsigned short*)&o1;
    pk.z = *(unsigned short*)&o2;
    pk.w = *(unsigned short*)&o3;
    *(ushort4*)(z2h + (size_t)wid * HDIM + 4 * l) = pk;
}

// ---- fused 8-step GRU + output projection, FP16 weights + v_dot2_f32_f16 ----
__global__ void k_gru_all(const __half* __restrict__ z2h, const float* __restrict__ Wih,
                          const float* __restrict__ Whh, const float* __restrict__ bih,
                          const float* __restrict__ bhh, const float* __restrict__ Wout,
                          const float* __restrict__ bout, float* __restrict__ out) {
    __shared__ __half sWih[3 * HDIM * 32];  // 6 KB, swizzled
    __shared__ __half sWhh[3 * HDIM * 32];
    __shared__ float sbih[3 * HDIM], sbhh[3 * HDIM], sWout[HDIM];
    __shared__ __half hls[GNB * 32];        // 1 KB
    __shared__ __half zls[GNB * 32];

    for (int i = threadIdx.x; i < 3 * HDIM * HDIM; i += 256) {
        int r = i >> 5, cc = i & 31;
        int key = (r ^ (r >> 3)) & 7;
        int pos = r * 32 + ((((cc >> 2) ^ key) << 2) | (cc & 3));
        sWih[pos] = __float2half_rn(Wih[i]);
        sWhh[pos] = __float2half_rn(Whh[i]);
    }
    for (int i = threadIdx.x; i < 3 * HDIM; i += 256) {
        sbih[i] = bih[i];
        sbhh[i] = bhh[i];
    }
    for (int i = threadIdx.x; i < HDIM; i += 256) sWout[i] = Wout[i];
    for (int i = threadIdx.x; i < GNB * 32; i += 256) hls[i] = __float2half_rn(0.f);
    __syncthreads();

    const int c = threadIdx.x & 31;
    const int nb = (threadIdx.x >> 5) * GNT;
    const int gbase = blockIdx.x * GNB;
    const int rR = c, rZ = HDIM + c, rN = 2 * HDIM + c;
    const int kR = (rR ^ (rR >> 3)) & 7;
    const int kZ = (rZ ^ (rZ >> 3)) & 7;
    const int kN = (rN ^ (rN >> 3)) & 7;

    const float br = sbih[c], bz = sbih[HDIM + c], bn = sbih[2 * HDIM + c];
    const float cr = sbhh[c], cz = sbhh[HDIM + c], cn = sbhh[2 * HDIM + c];

    float air0, aiz0, ain0, ahr0, ahz0, ahn0, hr0;
    float air1, aiz1, ain1, ahr1, ahz1, ahn1, hr1;
    hr0 = hr1 = 0.f;

    for (int t = 0; t < T_STEPS; ++t) {
        const uint2* zsrc = (const uint2*)(z2h + ((size_t)t * N_NODES + gbase) * HDIM);
        if (threadIdx.x < GNB * 8)
            *(uint2*)&zls[threadIdx.x * 4] = zsrc[threadIdx.x];
        __syncthreads();

        air0 = air1 = br;
        aiz0 = aiz1 = bz;
        ain0 = ain1 = bn;
        ahr0 = ahr1 = cr;
        ahz0 = ahz1 = cz;
        ahn0 = ahn1 = cn;
#pragma unroll 2
        for (int q = 0; q < 8; ++q) {
            int kq = q << 2;
            uint2 wri = *(const uint2*)&sWih[rR * 32 + ((q ^ kR) << 2)];
            uint2 wzi = *(const uint2*)&sWih[rZ * 32 + ((q ^ kZ) << 2)];
            uint2 wni = *(const uint2*)&sWih[rN * 32 + ((q ^ kN) << 2)];
            uint2 wrh = *(const uint2*)&sWhh[rR * 32 + ((q ^ kR) << 2)];
            uint2 wzh = *(const uint2*)&sWhh[rZ * 32 + ((q ^ kZ) << 2)];
            uint2 wnh = *(const uint2*)&sWhh[rN * 32 + ((q ^ kN) << 2)];
            uint2 zv0 = *(const uint2*)&zls[(nb + 0) * 32 + kq];
            uint2 hv0 = *(const uint2*)&hls[(nb + 0) * 32 + kq];
            uint2 zv1 = *(const uint2*)&zls[(nb + 1) * 32 + kq];
            uint2 hv1 = *(const uint2*)&hls[(nb + 1) * 32 + kq];
            air0 = dot4h(wri, zv0, air0);
            aiz0 = dot4h(wzi, zv0, aiz0);
            ain0 = dot4h(wni, zv0, ain0);
            ahr0 = dot4h(wrh, hv0, ahr0);
            ahz0 = dot4h(wzh, hv0, ahz0);
            ahn0 = dot4h(wnh, hv0, ahn0);
            air1 = dot4h(wri, zv1, air1);
            aiz1 = dot4h(wzi, zv1, aiz1);
            ain1 = dot4h(wni, zv1, ain1);
            ahr1 = dot4h(wrh, hv1, ahr1);
            ahz1 = dot4h(wzh, hv1, ahz1);
            ahn1 = dot4h(wnh, hv1, ahn1);
        }
        {
            float r = fsig(air0 + ahr0);
            float z = fsig(aiz0 + ahz0);
            float g = ftanh(ain0 + r * ahn0);
            hr0 = (1.f - z) * g + z * hr0;
            hls[(nb + 0) * 32 + c] = __float2half_rn(hr0);
        }
        {
            float r = fsig(air1 + ahr1);
            float z = fsig(aiz1 + ahz1);
            float g = ftanh(ain1 + r * ahn1);
            hr1 = (1.f - z) * g + z * hr1;
            hls[(nb + 1) * 32 + c] = __float2half_rn(hr1);
        }
        __syncthreads();
    }

    float wo = sWout[c];
    float s0 = lane32_sum(hr0 * wo);
    float s1 = lane32_sum(hr1 * wo);
    if (c == 0) {
        float bo = bout[0];
        out[gbase + nb + 0] = s0 + bo;
        out[gbase + nb + 1] = s1 + bo;
    }
}

extern "C" void kernel_launch(void* const* d_in, const int* in_sizes, int n_in,
                              void* d_out, int out_size, void* d_ws, size_t ws_size,
                              hipStream_t stream) {
    const float* x      = (const float*)d_in[0];   // T*N
    const int* eidx     = (const int*)d_in[1];     // T*2*E
    const float* W1     = (const float*)d_in[2];
    const float* a_src1 = (const float*)d_in[3];
    const float* a_dst1 = (const float*)d_in[4];
    const float* b1     = (const float*)d_in[5];
    const float* W2     = (const float*)d_in[6];
    const float* a_src2 = (const float*)d_in[7];
    const float* a_dst2 = (const float*)d_in[8];
    const float* b2     = (const float*)d_in[9];
    const float* W_ih   = (const float*)d_in[10];
    const float* W_hh   = (const float*)d_in[11];
    const float* b_ih   = (const float*)d_in[12];
    const float* b_hh   = (const float*)d_in[13];
    const float* W_out  = (const float*)d_in[14];
    const float* b_out  = (const float*)d_in[15];
    float* out = (float*)d_out;

    char* base_ws = (char*)d_ws;
    size_t off = 0;
    auto alloc = [&](size_t bytes) {
        char* p = base_ws + off;
        off = (off + bytes + 15) & ~(size_t)15;
        return p;
    };
    int* cnt             = (int*)alloc((size_t)TN * 4);
    int* row             = (int*)alloc((size_t)(TN + 1) * 4);
    int* bsum            = (int*)alloc((size_t)SCAN_BLOCKS * 4);
    int* bpre            = (int*)alloc((size_t)SCAN_BLOCKS * 4);
    float* inv           = (float*)alloc((size_t)TN * 2 * 4);
    __half* h2h          = (__half*)alloc((size_t)TN * HDIM * 2);   // 10.24 MB
    __half* sh           = (__half*)alloc((size_t)TN * 2);          // 320 KB
    float* ad2           = (float*)alloc((size_t)TN * 4);
    __half* z2h          = (__half*)alloc((size_t)TN * HDIM * 2);   // 10.24 MB
    float* S4            = (float*)alloc(16);
    unsigned short* es   = (unsigned short*)alloc((size_t)TE * 2);  // 10.24 MB
    int* bbase           = (int*)alloc((size_t)T_STEPS * GB * NPAIR * 4);   // 10.24 MB
    unsigned short* stagedG = (unsigned short*)alloc((size_t)TE * 2);       // 10.24 MB
    // Aliases (stream-order safe):
    //  h2h region = hist8 (5.12 MB u8) + lrow16 (5.12 MB u16): written by
    //  hist, read by blkpre/scatter; h2h written later by node1.
    unsigned char* hist8   = (unsigned char*)h2h;
    unsigned short* lrow16 = (unsigned short*)((char*)h2h + (size_t)T_STEPS * GB * N_NODES);

    const int B = 256;
    k_hist<<<8 * GB, 1024, 0, stream>>>(eidx, hist8, lrow16, stagedG);
    k_blkpre<<<(T_STEPS * NPAIR + B - 1) / B, B, 0, stream>>>(hist8, bbase, cnt,
                                                              W1, a_src1, a_dst1, S4);
    k_scan_a<<<SCAN_BLOCKS, B, 0, stream>>>(cnt, bsum);
    k_scan_b<<<1, B, 0, stream>>>(bsum, bpre);
    k_scan_c<<<SCAN_BLOCKS, B, 0, stream>>>(cnt, bpre, row);
    k_scatter<<<8 * GB, 512, 0, stream>>>(hist8, lrow16, row, bbase, stagedG, es);

    k_gat1red<<<TN / 256, B, 0, stream>>>(es, row, x, S4, inv);
    k_node1<<<TN / NPB, B, 0, stream>>>(inv, W1, b1, W2, a_src2, a_dst2, h2h, sh, ad2);
    k_gat2red<<<TN / 8, 64, 0, stream>>>(es, row, sh, ad2, h2h, b2, z2h);

    k_gru_all<<<N_NODES / GNB, B, 0, stream>>>(z2h, W_ih, W_hh, b_ih, b_hh, W_out, b_out, out);
}